// Round 1
// baseline (1459.617 us; speedup 1.0000x reference)
//
#include <hip/hip_runtime.h>
#include <math.h>

// B=1024, N=22, F_IN=32, T=32, K=3, CHEV=64, TIMEF=64
// x[b,n,f,t]: b-stride 22528, n-stride 1024, f-stride 32

__device__ __forceinline__ float sigm(float v){ return 1.f/(1.f+expf(-v)); }

// ---------------- K0: Chebyshev supports (T1 = row-softmax(relu(E E^T)), T2 = 2 T1 T1 - I) ----
__global__ void k_supports(const float* __restrict__ emb, float* __restrict__ wsT){
  __shared__ float M[484];
  __shared__ float T1s[484];
  int tid = threadIdx.x;
  if (tid < 484){
    int n = tid/22, m = tid - (tid/22)*22;
    float s = 0.f;
    for (int j=0;j<22;j++) s += emb[n*22+j]*emb[m*22+j];
    M[tid] = fmaxf(s, 0.f);
  }
  __syncthreads();
  if (tid < 22){ // softmax over axis=1 (row-wise over m)
    float mx = -1e30f;
    for (int m=0;m<22;m++) mx = fmaxf(mx, M[tid*22+m]);
    float s = 0.f;
    for (int m=0;m<22;m++) s += expf(M[tid*22+m]-mx);
    float inv = 1.f/s;
    for (int m=0;m<22;m++) T1s[tid*22+m] = expf(M[tid*22+m]-mx)*inv;
  }
  __syncthreads();
  if (tid < 484){
    int n = tid/22, m = tid - (tid/22)*22;
    float s = 0.f;
    for (int p=0;p<22;p++) s += T1s[n*22+p]*T1s[p*22+m];
    wsT[tid]      = T1s[tid];
    wsT[484+tid]  = 2.f*s - ((n==m)?1.f:0.f);
  }
}

// ---------------- K12: temporal attention (E_norm in LDS) + spatial attention -> S_norm ----
__global__ __launch_bounds__(256) void k_attn(
    const float* __restrict__ x,
    const float* __restrict__ U1, const float* __restrict__ U2, const float* __restrict__ U3,
    const float* __restrict__ be, const float* __restrict__ Ve,
    const float* __restrict__ W1, const float* __restrict__ W2, const float* __restrict__ W3,
    const float* __restrict__ bs, const float* __restrict__ Vs,
    float* __restrict__ snorm){
  int b = blockIdx.x, tid = threadIdx.x;
  const float* xb = x + (size_t)b*22528;
  __shared__ float xu1[1024];   // [f][t]
  __shared__ float rhs_t[704];  // [n][t]
  __shared__ float lhs_t[704];  // [t][n]
  __shared__ float sigp[1024];  // [s][u]
  __shared__ float Em[1024];    // [t][u]
  __shared__ float sm[1024];    // E_norm [t1][t2], col-softmax over t1
  __shared__ float w1e[32];
  __shared__ float xw3[704];    // [m][u]
  __shared__ float lhsS[704];   // [n][f]
  __shared__ float lhs2[704];   // [n][t]
  __shared__ float rhsS[704];   // [m][t]
  __shared__ float sig2[484];   // [m][l]
  __shared__ float Sl[484];     // [n][l]

  for (int idx=tid; idx<1024; idx+=256){
    float a=0.f;
    for (int n=0;n<22;n++) a = fmaf(xb[n*1024 + idx], U1[n], a);  // idx = f*32+t
    xu1[idx]=a;
  }
  for (int idx=tid; idx<704; idx+=256){
    int n = idx>>5, t = idx&31; float a=0.f, c=0.f;
    for (int f=0;f<32;f++){ float xv = xb[n*1024+f*32+t]; a = fmaf(U3[f],xv,a); c = fmaf(W3[f],xv,c); }
    rhs_t[idx]=a; xw3[idx]=c;
  }
  __syncthreads();
  for (int idx=tid; idx<704; idx+=256){
    int t = idx/22, n2 = idx - t*22; float a=0.f;
    for (int f=0;f<32;f++) a = fmaf(xu1[f*32+t], U2[f*22+n2], a);
    lhs_t[idx]=a;
  }
  __syncthreads();
  for (int idx=tid; idx<1024; idx+=256){
    int s = idx>>5, u = idx&31; float p=0.f;
    for (int n=0;n<22;n++) p = fmaf(lhs_t[s*22+n], rhs_t[n*32+u], p);
    sigp[idx] = sigm(p + be[idx]);
  }
  __syncthreads();
  for (int idx=tid; idx<1024; idx+=256){
    int t = idx>>5, u = idx&31; float a=0.f;
    for (int s2=0;s2<32;s2++) a = fmaf(Ve[t*32+s2], sigp[s2*32+u], a);
    Em[idx]=a;
  }
  __syncthreads();
  if (tid<32){ // softmax over first index t for fixed u  (axis=1 of [B,T,T])
    int u=tid; float mx=-1e30f;
    for (int t=0;t<32;t++) mx = fmaxf(mx, Em[t*32+u]);
    float s=0.f; for (int t=0;t<32;t++) s += expf(Em[t*32+u]-mx);
    float inv = 1.f/s;
    for (int t=0;t<32;t++) sm[t*32+u] = expf(Em[t*32+u]-mx)*inv;
  }
  __syncthreads();
  if (tid<32){ float a=0.f; for (int t2=0;t2<32;t2++) a = fmaf(sm[tid*32+t2], W1[t2], a); w1e[tid]=a; }
  __syncthreads();
  for (int idx=tid; idx<704; idx+=256){
    int n = idx>>5, f = idx&31; float a=0.f;
    for (int u=0;u<32;u++) a = fmaf(xb[n*1024+f*32+u], w1e[u], a);
    lhsS[idx]=a;
  }
  __syncthreads();
  for (int idx=tid; idx<704; idx+=256){
    int n = idx>>5, t = idx&31; float a=0.f;
    for (int f=0;f<32;f++) a = fmaf(lhsS[n*32+f], W2[f*32+t], a);
    lhs2[idx]=a;
  }
  for (int idx=tid; idx<704; idx+=256){
    int mm = idx>>5, t = idx&31; float a=0.f;
    for (int u=0;u<32;u++) a = fmaf(xw3[mm*32+u], sm[u*32+t], a);
    rhsS[idx]=a;
  }
  __syncthreads();
  for (int idx=tid; idx<484; idx+=256){
    int a_ = idx/22, l = idx - (idx/22)*22; float p=0.f;
    for (int t=0;t<32;t++) p = fmaf(lhs2[a_*32+t], rhsS[l*32+t], p);
    sig2[idx] = sigm(p + bs[idx]);
  }
  __syncthreads();
  for (int idx=tid; idx<484; idx+=256){
    int n = idx/22, l = idx - (idx/22)*22; float s=0.f;
    for (int mm=0;mm<22;mm++) s = fmaf(Vs[n*22+mm], sig2[mm*22+l], s);
    Sl[idx]=s;
  }
  __syncthreads();
  if (tid<22){ // softmax over n for fixed l (axis=1 of [B,N,N])
    int l=tid; float mx=-1e30f;
    for (int n=0;n<22;n++) mx = fmaxf(mx, Sl[n*22+l]);
    float s=0.f; for (int n=0;n<22;n++) s += expf(Sl[n*22+l]-mx);
    float inv=1.f/s;
    for (int n=0;n<22;n++) snorm[(size_t)b*484 + n*22 + l] = expf(Sl[n*22+l]-mx)*inv;
  }
}

// ---------------- K3a: cheb conv + Theta GEMM + relu -> sgcn (stored in d_out as scratch) ----
__global__ __launch_bounds__(256) void k_cheb(
    const float* __restrict__ x, const float* __restrict__ Theta,
    const float* __restrict__ wsT, const float* __restrict__ snorm,
    float* __restrict__ sg){
  int bm = blockIdx.x;
  int b = bm/22, m = bm - b*22;
  int tid = threadIdx.x;
  __shared__ __align__(16) float th[6144];   // Theta [kf=96][c=64]
  __shared__ __align__(16) float G[3072];    // [kf=96][t=32]
  __shared__ __align__(16) float P[2048];    // split-k partials [c][t]
  __shared__ float ak[66];                   // A_k[:,m], k=0..2
  for (int i=tid;i<6144;i+=256) th[i] = Theta[i];
  if (tid < 66){
    int k = tid/22, n = tid - (tid/22)*22;
    float tk = (k==0) ? ((n==m)?1.f:0.f) : wsT[(k-1)*484 + n*22 + m];
    ak[tid] = tk * snorm[(size_t)b*484 + n*22 + m];
  }
  __syncthreads();
  const float* xb = x + (size_t)b*22528;
  #pragma unroll
  for (int p=0;p<4;p++){
    int idx = tid + p*256;          // idx = f*32+t
    float a0=0.f, a1=0.f, a2=0.f;
    #pragma unroll
    for (int n=0;n<22;n++){
      float xv = xb[n*1024 + idx];
      a0 = fmaf(ak[n],    xv, a0);
      a1 = fmaf(ak[22+n], xv, a1);
      a2 = fmaf(ak[44+n], xv, a2);
    }
    G[idx] = a0; G[1024+idx] = a1; G[2048+idx] = a2;
  }
  __syncthreads();
  // 2-way split-k GEMM: [96kf] x -> [64c][32t], 4x4 register tiles
  int half = tid>>7, r = tid&127;
  int cq = r>>3, tq = r&7;
  float acc[4][4];
  #pragma unroll
  for (int i=0;i<4;i++){
    #pragma unroll
    for (int j=0;j<4;j++) acc[i][j]=0.f;
  }
  const float4* G4  = (const float4*)G;
  const float4* th4 = (const float4*)th;
  int kf0 = half*48;
  for (int kk=0;kk<48;kk++){
    int kf = kf0 + kk;
    float4 gv = G4[kf*8 + tq];
    float4 wv = th4[kf*16 + cq];
    float gg[4] = {gv.x,gv.y,gv.z,gv.w};
    float ww[4] = {wv.x,wv.y,wv.z,wv.w};
    #pragma unroll
    for (int i=0;i<4;i++){
      #pragma unroll
      for (int j=0;j<4;j++) acc[i][j] = fmaf(ww[i], gg[j], acc[i][j]);
    }
  }
  float4* P4 = (float4*)P;
  if (half==1){
    #pragma unroll
    for (int i=0;i<4;i++){
      float4 v; v.x=acc[i][0]; v.y=acc[i][1]; v.z=acc[i][2]; v.w=acc[i][3];
      P4[(cq*4+i)*8 + tq] = v;
    }
  }
  __syncthreads();
  if (half==0){
    float4* out4 = (float4*)(sg + (size_t)bm*2048);
    #pragma unroll
    for (int i=0;i<4;i++){
      float4 pv = P4[(cq*4+i)*8 + tq];
      float4 v;
      v.x = fmaxf(acc[i][0]+pv.x, 0.f);
      v.y = fmaxf(acc[i][1]+pv.y, 0.f);
      v.z = fmaxf(acc[i][2]+pv.z, 0.f);
      v.w = fmaxf(acc[i][3]+pv.w, 0.f);
      out4[(cq*4+i)*8 + tq] = v;
    }
  }
}

// ---------------- K3b: tconv(1x3) + rconv(1x1) + relu + LayerNorm -> out (in place over sgcn) ----
__global__ __launch_bounds__(256) void k_tail(
    const float* __restrict__ x,
    const float* __restrict__ tw, const float* __restrict__ tb,
    const float* __restrict__ rw, const float* __restrict__ rb,
    const float* __restrict__ lng, const float* __restrict__ lnb,
    float* __restrict__ out){
  int bm = blockIdx.x;
  int b = bm/22, m = bm - b*22;
  int tid = threadIdx.x;
  __shared__ __align__(16) float sgl[64*36];   // sg[c][tt], tt=t+1, zero pads at 0 and 33..35
  __shared__ __align__(16) float xl[1024];     // x[b,m][f][t]
  __shared__ float wtl[64*193];                // tconv_w padded rows (kills stride-192 bank conflict)
  __shared__ float rwl[64*33];                 // rconv_w padded
  __shared__ float part[3*2112];               // split-c partials, padded o*33+t
  __shared__ float ybuf[64*33];
  __shared__ float mus[32], rss[32];

  const float* sgp = out + (size_t)bm*2048;
  for (int i=tid;i<2048;i+=256){ int c=i>>5, t=i&31; sgl[c*36 + t + 1] = sgp[i]; }
  { int c = tid>>2, j = tid&3; sgl[c*36 + ((j==0)?0:(32+j))] = 0.f; }
  for (int i=tid;i<1024;i+=256) xl[i] = x[(size_t)b*22528 + m*1024 + i];
  for (int i=tid;i<12288;i+=256){ int o = i/192, j = i - o*192; wtl[o*193 + j] = tw[i]; }
  for (int i=tid;i<2048;i+=256){ int o = i>>5, f = i&31; rwl[o*33 + f] = rw[i]; }
  __syncthreads();

  int o = tid & 63;     // lane = o within each wave (sg row reads broadcast)
  int q = tid >> 6;     // wave = c-quarter
  float acc[32];
  #pragma unroll
  for (int t=0;t<32;t++) acc[t]=0.f;
  const float4* sg4 = (const float4*)sgl;
  const float* wrow = &wtl[o*193];
  for (int ci=0; ci<16; ci++){
    int c = q*16 + ci;
    float w0 = wrow[c*3+0], w1 = wrow[c*3+1], w2 = wrow[c*3+2];
    float4 rv[9];
    #pragma unroll
    for (int z=0;z<9;z++) rv[z] = sg4[c*9 + z];
    const float* row = (const float*)rv;
    #pragma unroll
    for (int t=0;t<32;t++)
      acc[t] = fmaf(w0,row[t], fmaf(w1,row[t+1], fmaf(w2,row[t+2], acc[t])));
  }
  if (q != 0){
    #pragma unroll
    for (int t=0;t<32;t++) part[(q-1)*2112 + o*33 + t] = acc[t];
  }
  __syncthreads();
  if (q == 0){
    #pragma unroll
    for (int t=0;t<32;t++)
      acc[t] += part[o*33+t] + part[2112 + o*33+t] + part[2*2112 + o*33+t];
    const float4* xl4 = (const float4*)xl;
    for (int f=0;f<32;f++){
      float w = rwl[o*33+f];
      float4 xr[8];
      #pragma unroll
      for (int z=0;z<8;z++) xr[z] = xl4[f*8 + z];
      const float* xrow = (const float*)xr;
      #pragma unroll
      for (int t=0;t<32;t++) acc[t] = fmaf(w, xrow[t], acc[t]);
    }
    float bias = tb[o] + rb[o];
    #pragma unroll
    for (int t=0;t<32;t++){
      float v = fmaxf(acc[t] + bias, 0.f);
      acc[t] = v;
      ybuf[o*33 + t] = v;
    }
  }
  __syncthreads();
  if (tid < 32){
    int t = tid;
    float s = 0.f;
    for (int oo=0;oo<64;oo++) s += ybuf[oo*33+t];
    float mu = s * (1.f/64.f);
    float v = 0.f;
    for (int oo=0;oo<64;oo++){ float d = ybuf[oo*33+t]-mu; v = fmaf(d,d,v); }
    mus[t] = mu;
    rss[t] = rsqrtf(v*(1.f/64.f) + 1e-5f);
  }
  __syncthreads();
  if (q == 0){
    float gv = lng[o], bv = lnb[o];
    float4* o4 = (float4*)(out + (size_t)bm*2048 + o*32);
    #pragma unroll
    for (int z=0;z<8;z++){
      float4 v;
      v.x = (acc[z*4+0]-mus[z*4+0])*rss[z*4+0]*gv + bv;
      v.y = (acc[z*4+1]-mus[z*4+1])*rss[z*4+1]*gv + bv;
      v.z = (acc[z*4+2]-mus[z*4+2])*rss[z*4+2]*gv + bv;
      v.w = (acc[z*4+3]-mus[z*4+3])*rss[z*4+3]*gv + bv;
      o4[z] = v;
    }
  }
}

extern "C" void kernel_launch(void* const* d_in, const int* in_sizes, int n_in,
                              void* d_out, int out_size, void* d_ws, size_t ws_size,
                              hipStream_t stream){
  const float* x     = (const float*)d_in[0];
  const float* U1    = (const float*)d_in[1];
  const float* U2    = (const float*)d_in[2];
  const float* U3    = (const float*)d_in[3];
  const float* be    = (const float*)d_in[4];
  const float* Ve    = (const float*)d_in[5];
  const float* W1    = (const float*)d_in[6];
  const float* W2    = (const float*)d_in[7];
  const float* W3    = (const float*)d_in[8];
  const float* bs    = (const float*)d_in[9];
  const float* Vs    = (const float*)d_in[10];
  const float* Theta = (const float*)d_in[11];
  const float* emb   = (const float*)d_in[12];
  const float* tw    = (const float*)d_in[13];
  const float* tb    = (const float*)d_in[14];
  const float* rw    = (const float*)d_in[15];
  const float* rb    = (const float*)d_in[16];
  const float* lng   = (const float*)d_in[17];
  const float* lnb   = (const float*)d_in[18];
  float* out = (float*)d_out;
  float* wsf = (float*)d_ws;
  float* wsT   = wsf;          // 968 floats: T1(484), T2(484)
  float* snorm = wsf + 1024;   // 1024*484 floats (~1.9 MB)

  k_supports<<<1, 512, 0, stream>>>(emb, wsT);
  k_attn<<<1024, 256, 0, stream>>>(x, U1,U2,U3, be,Ve, W1,W2,W3, bs,Vs, snorm);
  k_cheb<<<1024*22, 256, 0, stream>>>(x, Theta, wsT, snorm, out);
  k_tail<<<1024*22, 256, 0, stream>>>(x, tw, tb, rw, rb, lng, lnb, out);
}

// Round 2
// 929.701 us; speedup vs baseline: 1.5700x; 1.5700x over previous
//
#include <hip/hip_runtime.h>
#include <math.h>

// B=1024, N=22, F_IN=32, T=32, K=3, CHEV=64, TIMEF=64
// x[b,n,f,t]: b-stride 22528, n-stride 1024, f-stride 32

__device__ __forceinline__ float sigm(float v){ return 1.f/(1.f+expf(-v)); }

// ---------------- K0: Chebyshev supports (T1 = row-softmax(relu(E E^T)), T2 = 2 T1 T1 - I) ----
__global__ void k_supports(const float* __restrict__ emb, float* __restrict__ wsT){
  __shared__ float M[484];
  __shared__ float T1s[484];
  int tid = threadIdx.x;
  if (tid < 484){
    int n = tid/22, m = tid - (tid/22)*22;
    float s = 0.f;
    for (int j=0;j<22;j++) s += emb[n*22+j]*emb[m*22+j];
    M[tid] = fmaxf(s, 0.f);
  }
  __syncthreads();
  if (tid < 22){ // softmax over axis=1 (row-wise over m)
    float mx = -1e30f;
    for (int m=0;m<22;m++) mx = fmaxf(mx, M[tid*22+m]);
    float s = 0.f;
    for (int m=0;m<22;m++) s += expf(M[tid*22+m]-mx);
    float inv = 1.f/s;
    for (int m=0;m<22;m++) T1s[tid*22+m] = expf(M[tid*22+m]-mx)*inv;
  }
  __syncthreads();
  if (tid < 484){
    int n = tid/22, m = tid - (tid/22)*22;
    float s = 0.f;
    for (int p=0;p<22;p++) s += T1s[n*22+p]*T1s[p*22+m];
    wsT[tid]      = T1s[tid];
    wsT[484+tid]  = 2.f*s - ((n==m)?1.f:0.f);
  }
}

// ---------------- K_prep: transpose tconv/rconv weights -> W[k=224][o=64], fold bias ----
__global__ void k_prep(const float* __restrict__ tw, const float* __restrict__ tb,
                       const float* __restrict__ rw, const float* __restrict__ rb,
                       float* __restrict__ wsW, float* __restrict__ wsB){
  int tid = blockIdx.x*256 + threadIdx.x;
  if (tid < 12288){ int o = tid/192, k = tid - o*192; wsW[k*64 + o] = tw[tid]; }
  else if (tid < 14336){ int i = tid - 12288; int o = i>>5, f = i&31; wsW[(192+f)*64 + o] = rw[i]; }
  if (tid < 64) wsB[tid] = tb[tid] + rb[tid];
}

// ---------------- K12: temporal attention (E_norm in LDS) + spatial attention -> S_norm ----
__global__ __launch_bounds__(256) void k_attn(
    const float* __restrict__ x,
    const float* __restrict__ U1, const float* __restrict__ U2, const float* __restrict__ U3,
    const float* __restrict__ be, const float* __restrict__ Ve,
    const float* __restrict__ W1, const float* __restrict__ W2, const float* __restrict__ W3,
    const float* __restrict__ bs, const float* __restrict__ Vs,
    float* __restrict__ snorm){
  int b = blockIdx.x, tid = threadIdx.x;
  const float* xb = x + (size_t)b*22528;
  __shared__ float xu1[1024];   // [f][t]
  __shared__ float rhs_t[704];  // [n][t]
  __shared__ float lhs_t[704];  // [t][n]
  __shared__ float sigp[1024];  // [s][u]
  __shared__ float Em[1024];    // [t][u]
  __shared__ float sm[1024];    // E_norm [t1][t2], col-softmax over t1
  __shared__ float w1e[32];
  __shared__ float xw3[704];    // [m][u]
  __shared__ float lhsS[704];   // [n][f]
  __shared__ float lhs2[704];   // [n][t]
  __shared__ float rhsS[704];   // [m][t]
  __shared__ float sig2[484];   // [m][l]
  __shared__ float Sl[484];     // [n][l]

  for (int idx=tid; idx<1024; idx+=256){
    float a=0.f;
    for (int n=0;n<22;n++) a = fmaf(xb[n*1024 + idx], U1[n], a);  // idx = f*32+t
    xu1[idx]=a;
  }
  for (int idx=tid; idx<704; idx+=256){
    int n = idx>>5, t = idx&31; float a=0.f, c=0.f;
    for (int f=0;f<32;f++){ float xv = xb[n*1024+f*32+t]; a = fmaf(U3[f],xv,a); c = fmaf(W3[f],xv,c); }
    rhs_t[idx]=a; xw3[idx]=c;
  }
  __syncthreads();
  for (int idx=tid; idx<704; idx+=256){
    int t = idx/22, n2 = idx - t*22; float a=0.f;
    for (int f=0;f<32;f++) a = fmaf(xu1[f*32+t], U2[f*22+n2], a);
    lhs_t[idx]=a;
  }
  __syncthreads();
  for (int idx=tid; idx<1024; idx+=256){
    int s = idx>>5, u = idx&31; float p=0.f;
    for (int n=0;n<22;n++) p = fmaf(lhs_t[s*22+n], rhs_t[n*32+u], p);
    sigp[idx] = sigm(p + be[idx]);
  }
  __syncthreads();
  for (int idx=tid; idx<1024; idx+=256){
    int t = idx>>5, u = idx&31; float a=0.f;
    for (int s2=0;s2<32;s2++) a = fmaf(Ve[t*32+s2], sigp[s2*32+u], a);
    Em[idx]=a;
  }
  __syncthreads();
  if (tid<32){ // softmax over first index t for fixed u  (axis=1 of [B,T,T])
    int u=tid; float mx=-1e30f;
    for (int t=0;t<32;t++) mx = fmaxf(mx, Em[t*32+u]);
    float s=0.f; for (int t=0;t<32;t++) s += expf(Em[t*32+u]-mx);
    float inv = 1.f/s;
    for (int t=0;t<32;t++) sm[t*32+u] = expf(Em[t*32+u]-mx)*inv;
  }
  __syncthreads();
  if (tid<32){ float a=0.f; for (int t2=0;t2<32;t2++) a = fmaf(sm[tid*32+t2], W1[t2], a); w1e[tid]=a; }
  __syncthreads();
  for (int idx=tid; idx<704; idx+=256){
    int n = idx>>5, f = idx&31; float a=0.f;
    for (int u=0;u<32;u++) a = fmaf(xb[n*1024+f*32+u], w1e[u], a);
    lhsS[idx]=a;
  }
  __syncthreads();
  for (int idx=tid; idx<704; idx+=256){
    int n = idx>>5, t = idx&31; float a=0.f;
    for (int f=0;f<32;f++) a = fmaf(lhsS[n*32+f], W2[f*32+t], a);
    lhs2[idx]=a;
  }
  for (int idx=tid; idx<704; idx+=256){
    int mm = idx>>5, t = idx&31; float a=0.f;
    for (int u=0;u<32;u++) a = fmaf(xw3[mm*32+u], sm[u*32+t], a);
    rhsS[idx]=a;
  }
  __syncthreads();
  for (int idx=tid; idx<484; idx+=256){
    int a_ = idx/22, l = idx - (idx/22)*22; float p=0.f;
    for (int t=0;t<32;t++) p = fmaf(lhs2[a_*32+t], rhsS[l*32+t], p);
    sig2[idx] = sigm(p + bs[idx]);
  }
  __syncthreads();
  for (int idx=tid; idx<484; idx+=256){
    int n = idx/22, l = idx - (idx/22)*22; float s=0.f;
    for (int mm=0;mm<22;mm++) s = fmaf(Vs[n*22+mm], sig2[mm*22+l], s);
    Sl[idx]=s;
  }
  __syncthreads();
  if (tid<22){ // softmax over n for fixed l (axis=1 of [B,N,N])
    int l=tid; float mx=-1e30f;
    for (int n=0;n<22;n++) mx = fmaxf(mx, Sl[n*22+l]);
    float s=0.f; for (int n=0;n<22;n++) s += expf(Sl[n*22+l]-mx);
    float inv=1.f/s;
    for (int n=0;n<22;n++) snorm[(size_t)b*484 + n*22 + l] = expf(Sl[n*22+l]-mx)*inv;
  }
}

// ---------------- Fused: cheb conv + Theta GEMM + relu + tconv + rconv + relu + LN ----
// One block per (b,m). 256 threads, 4x2 register tiles for both GEMMs.
// LDS ~26KB. Weights (pre-transposed) + Theta read from global (L1/L2-resident).
__global__ __launch_bounds__(256, 4) void k_fused(
    const float* __restrict__ x, const float* __restrict__ Theta,
    const float* __restrict__ wsT, const float* __restrict__ snorm,
    const float* __restrict__ wsW, const float* __restrict__ wsB,
    const float* __restrict__ lng, const float* __restrict__ lnb,
    float* __restrict__ out){
  __shared__ __align__(16) float G[3072];    // [kf=96][t=32]; reused as ybuf[64][33] at end
  __shared__ __align__(16) float sgl[2304];  // sg padded [c=64][36]: col0 & col33 zero
  __shared__ __align__(16) float xl[1024];   // x[b,m][f][t]
  __shared__ float ak[66];                   // A_k[:,m] * snorm[:,m], k=0..2

  int wg = blockIdx.x;
  int logical = (wg & 7)*2816 + (wg >> 3);   // chunked XCD swizzle: same-b blocks share an XCD L2
  int b = logical/22, m = logical - b*22;
  int tid = threadIdx.x;
  const float* xb = x + (size_t)b*22528;

  { int c = tid>>2, z = tid&3; sgl[c*36 + ((z==0)?0:(32+z))] = 0.f; } // conv zero pads
  if (tid < 66){
    int k = tid/22, n = tid - (tid/22)*22;
    float tk = (k==0) ? ((n==m)?1.f:0.f) : wsT[(k-1)*484 + n*22 + m];
    ak[tid] = tk * snorm[(size_t)b*484 + n*22 + m];
  }
  for (int i=tid;i<1024;i+=256) xl[i] = xb[m*1024 + i];
  __syncthreads();

  // Phase A: G[k*32+f][t] = sum_n ak[k,n] * x[n,f,t]
  #pragma unroll
  for (int p=0;p<4;p++){
    int idx = tid + p*256;            // idx = f*32+t
    float a0=0.f, a1=0.f, a2=0.f;
    #pragma unroll
    for (int n=0;n<22;n++){
      float xv = xb[n*1024 + idx];
      a0 = fmaf(ak[n],    xv, a0);
      a1 = fmaf(ak[22+n], xv, a1);
      a2 = fmaf(ak[44+n], xv, a2);
    }
    G[idx] = a0; G[1024+idx] = a1; G[2048+idx] = a2;
  }
  __syncthreads();

  int cq = tid & 15, tq = tid >> 4;   // 16 x 16
  int o0 = cq*4, t0 = tq*2;

  // Phase B: sg[c][t] = relu( sum_kf Theta[kf][c] * G[kf][t] ), K=96
  {
    float acc[4][2];
    #pragma unroll
    for (int i=0;i<4;i++){ acc[i][0]=0.f; acc[i][1]=0.f; }
    const float4* th4 = (const float4*)Theta;
    #pragma unroll 4
    for (int kf=0; kf<96; kf++){
      float4 wv = th4[kf*16 + cq];
      float2 gv = *(const float2*)&G[kf*32 + t0];
      float ww[4] = {wv.x, wv.y, wv.z, wv.w};
      #pragma unroll
      for (int i=0;i<4;i++){
        acc[i][0] = fmaf(ww[i], gv.x, acc[i][0]);
        acc[i][1] = fmaf(ww[i], gv.y, acc[i][1]);
      }
    }
    #pragma unroll
    for (int i=0;i<4;i++){
      sgl[(o0+i)*36 + 1 + t0]     = fmaxf(acc[i][0], 0.f);
      sgl[(o0+i)*36 + 1 + t0 + 1] = fmaxf(acc[i][1], 0.f);
    }
  }
  __syncthreads();

  // Phase C: out[o][t] = sum_{c,dt} tw[o][c][dt]*sgl[c][t+dt] + sum_f rw[o][f]*xl[f][t]
  float acc[4][2];
  #pragma unroll
  for (int i=0;i<4;i++){ acc[i][0]=0.f; acc[i][1]=0.f; }
  const float4* W4 = (const float4*)wsW;
  #pragma unroll 2
  for (int c=0;c<64;c++){
    float4 w0 = W4[(c*3+0)*16 + cq];
    float4 w1 = W4[(c*3+1)*16 + cq];
    float4 w2 = W4[(c*3+2)*16 + cq];
    const float* row = &sgl[c*36 + t0];
    float s0=row[0], s1=row[1], s2=row[2], s3=row[3];
    float a0[4]={w0.x,w0.y,w0.z,w0.w}, a1[4]={w1.x,w1.y,w1.z,w1.w}, a2[4]={w2.x,w2.y,w2.z,w2.w};
    #pragma unroll
    for (int i=0;i<4;i++){
      acc[i][0] = fmaf(a0[i],s0, fmaf(a1[i],s1, fmaf(a2[i],s2, acc[i][0])));
      acc[i][1] = fmaf(a0[i],s1, fmaf(a1[i],s2, fmaf(a2[i],s3, acc[i][1])));
    }
  }
  #pragma unroll 4
  for (int f=0;f<32;f++){
    float4 wr = W4[(192+f)*16 + cq];
    float x0 = xl[f*32 + t0], x1 = xl[f*32 + t0 + 1];
    float a[4]={wr.x,wr.y,wr.z,wr.w};
    #pragma unroll
    for (int i=0;i<4;i++){
      acc[i][0] = fmaf(a[i], x0, acc[i][0]);
      acc[i][1] = fmaf(a[i], x1, acc[i][1]);
    }
  }

  // bias + relu + LayerNorm over o (64) per t
  float4 bias4 = ((const float4*)wsB)[cq];
  float bb[4] = {bias4.x, bias4.y, bias4.z, bias4.w};
  float y[4][2];
  float s1j[2] = {0.f, 0.f}, s2j[2] = {0.f, 0.f};
  #pragma unroll
  for (int i=0;i<4;i++){
    #pragma unroll
    for (int j=0;j<2;j++){
      float v = fmaxf(acc[i][j] + bb[i], 0.f);
      y[i][j] = v;
      s1j[j] += v;
      s2j[j] = fmaf(v, v, s2j[j]);
    }
  }
  // reduce across the 16 cq lanes (same tq): masks 1,2,4,8 stay in-group
  #pragma unroll
  for (int mask=1; mask<16; mask<<=1){
    s1j[0] += __shfl_xor(s1j[0], mask);
    s1j[1] += __shfl_xor(s1j[1], mask);
    s2j[0] += __shfl_xor(s2j[0], mask);
    s2j[1] += __shfl_xor(s2j[1], mask);
  }
  float4 g4 = ((const float4*)lng)[cq];
  float4 be4 = ((const float4*)lnb)[cq];
  float gg[4]={g4.x,g4.y,g4.z,g4.w}, bg[4]={be4.x,be4.y,be4.z,be4.w};
  #pragma unroll
  for (int j=0;j<2;j++){
    float mu = s1j[j] * (1.f/64.f);
    float var = s2j[j] * (1.f/64.f) - mu*mu;
    float rs = rsqrtf(var + 1e-5f);
    #pragma unroll
    for (int i=0;i<4;i++)
      G[(o0+i)*33 + t0 + j] = (y[i][j] - mu)*rs*gg[i] + bg[i];  // G reused as ybuf
  }
  __syncthreads();
  float* ob = out + (size_t)logical*2048;
  #pragma unroll
  for (int p=0;p<8;p++){
    int idx = tid + p*256;
    ob[idx] = G[(idx>>5)*33 + (idx&31)];
  }
}

extern "C" void kernel_launch(void* const* d_in, const int* in_sizes, int n_in,
                              void* d_out, int out_size, void* d_ws, size_t ws_size,
                              hipStream_t stream){
  const float* x     = (const float*)d_in[0];
  const float* U1    = (const float*)d_in[1];
  const float* U2    = (const float*)d_in[2];
  const float* U3    = (const float*)d_in[3];
  const float* be    = (const float*)d_in[4];
  const float* Ve    = (const float*)d_in[5];
  const float* W1    = (const float*)d_in[6];
  const float* W2    = (const float*)d_in[7];
  const float* W3    = (const float*)d_in[8];
  const float* bs    = (const float*)d_in[9];
  const float* Vs    = (const float*)d_in[10];
  const float* Theta = (const float*)d_in[11];
  const float* emb   = (const float*)d_in[12];
  const float* tw    = (const float*)d_in[13];
  const float* tb    = (const float*)d_in[14];
  const float* rw    = (const float*)d_in[15];
  const float* rb    = (const float*)d_in[16];
  const float* lng   = (const float*)d_in[17];
  const float* lnb   = (const float*)d_in[18];
  float* out = (float*)d_out;
  float* wsf = (float*)d_ws;
  float* wsT   = wsf;              // 968 floats (pad to 1024)
  float* snorm = wsf + 1024;       // 1024*484 = 495616 floats
  float* wsW   = wsf + 496640;     // 224*64 = 14336 floats
  float* wsB   = wsf + 510976;     // 64 floats

  k_supports<<<1, 512, 0, stream>>>(emb, wsT);
  k_prep<<<56, 256, 0, stream>>>(tw, tb, rw, rb, wsW, wsB);
  k_attn<<<1024, 256, 0, stream>>>(x, U1,U2,U3, be,Ve, W1,W2,W3, bs,Vs, snorm);
  k_fused<<<1024*22, 256, 0, stream>>>(x, Theta, wsT, snorm, wsW, wsB, lng, lnb, out);
}

// Round 3
// 199.283 us; speedup vs baseline: 7.3243x; 4.6652x over previous
//
#include <hip/hip_runtime.h>
#include <math.h>

// B=1024, N=22, F_IN=32, T=32, K=3, CHEV=64, TIMEF=64
// x[b,n,f,t]: b-stride 22528, n-stride 1024, f-stride 32

typedef unsigned short u16;
typedef __attribute__((ext_vector_type(8))) short short8;
typedef __attribute__((ext_vector_type(4))) float f32x4;

__device__ __forceinline__ float sigm(float v){ return 1.f/(1.f+expf(-v)); }

__device__ __forceinline__ u16 f2bf(float x){
  union { float f; unsigned u; } c; c.f = x;
  unsigned r = (c.u + 0x7fffu + ((c.u>>16)&1u)) >> 16;
  return (u16)r;
}

// ---------------- K0: Chebyshev supports (T1 = row-softmax(relu(E E^T)), T2 = 2 T1 T1 - I) ----
__global__ void k_supports(const float* __restrict__ emb, float* __restrict__ wsT){
  __shared__ float M[484];
  __shared__ float T1s[484];
  int tid = threadIdx.x;
  if (tid < 484){
    int n = tid/22, m = tid - (tid/22)*22;
    float s = 0.f;
    for (int j=0;j<22;j++) s += emb[n*22+j]*emb[m*22+j];
    M[tid] = fmaxf(s, 0.f);
  }
  __syncthreads();
  if (tid < 22){
    float mx = -1e30f;
    for (int m=0;m<22;m++) mx = fmaxf(mx, M[tid*22+m]);
    float s = 0.f;
    for (int m=0;m<22;m++) s += expf(M[tid*22+m]-mx);
    float inv = 1.f/s;
    for (int m=0;m<22;m++) T1s[tid*22+m] = expf(M[tid*22+m]-mx)*inv;
  }
  __syncthreads();
  if (tid < 484){
    int n = tid/22, m = tid - (tid/22)*22;
    float s = 0.f;
    for (int p=0;p<22;p++) s += T1s[n*22+p]*T1s[p*22+m];
    wsT[tid]      = T1s[tid];
    wsT[484+tid]  = 2.f*s - ((n==m)?1.f:0.f);
  }
}

// ---------------- K_prep: pack Theta / tconv+rconv weights into bf16 MFMA A-fragment layout ----
// thA[((ks*4+ci)*64 + l)*8 + j] = Theta[kf=32ks+8*(l>>4)+j][c=16ci+(l&15)]   (K=96)
// wA [((ks*4+oi)*64 + l)*8 + j] = Wmat[k=32ks+8*(l>>4)+j][o=16oi+(l&15)]    (K=224)
//   Wmat[k][o]: k<192 -> tw[o][c=k&63][dt=k>>6] ; k>=192 -> rw[o][k-192]
__global__ void k_prep(const float* __restrict__ Theta,
                       const float* __restrict__ tw, const float* __restrict__ tb,
                       const float* __restrict__ rw, const float* __restrict__ rb,
                       u16* __restrict__ thA, u16* __restrict__ wA, float* __restrict__ wsB){
  int tid = blockIdx.x*256 + threadIdx.x;
  if (tid < 6144){
    int j = tid&7, l = (tid>>3)&63, blk = tid>>9;      // blk 0..11
    int ks = blk>>2, ci = blk&3, r = l&15, g = l>>4;
    int kf = 32*ks + 8*g + j, c = 16*ci + r;
    thA[tid] = f2bf(Theta[kf*64 + c]);
  } else if (tid < 20480){
    int e = tid - 6144;
    int j = e&7, l = (e>>3)&63, blk = e>>9;            // blk 0..27
    int ks = blk>>2, oi = blk&3, r = l&15, g = l>>4;
    int k = 32*ks + 8*g + j, o = 16*oi + r;
    float v = (k < 192) ? tw[o*192 + (k&63)*3 + (k>>6)] : rw[o*32 + (k-192)];
    wA[e] = f2bf(v);
  } else if (tid < 20544){
    int o = tid - 20480; wsB[o] = tb[o] + rb[o];
  }
}

// ---------------- K12: temporal attention (E_norm in LDS) + spatial attention -> S_norm ----
__global__ __launch_bounds__(256) void k_attn(
    const float* __restrict__ x,
    const float* __restrict__ U1, const float* __restrict__ U2, const float* __restrict__ U3,
    const float* __restrict__ be, const float* __restrict__ Ve,
    const float* __restrict__ W1, const float* __restrict__ W2, const float* __restrict__ W3,
    const float* __restrict__ bs, const float* __restrict__ Vs,
    float* __restrict__ snorm){
  int b = blockIdx.x, tid = threadIdx.x;
  const float* xb = x + (size_t)b*22528;
  __shared__ float xu1[1024];
  __shared__ float rhs_t[704];
  __shared__ float lhs_t[704];
  __shared__ float sigp[1024];
  __shared__ float Em[1024];
  __shared__ float sm[1024];
  __shared__ float w1e[32];
  __shared__ float xw3[704];
  __shared__ float lhsS[704];
  __shared__ float lhs2[704];
  __shared__ float rhsS[704];
  __shared__ float sig2[484];
  __shared__ float Sl[484];

  for (int idx=tid; idx<1024; idx+=256){
    float a=0.f;
    for (int n=0;n<22;n++) a = fmaf(xb[n*1024 + idx], U1[n], a);
    xu1[idx]=a;
  }
  for (int idx=tid; idx<704; idx+=256){
    int n = idx>>5, t = idx&31; float a=0.f, c=0.f;
    for (int f=0;f<32;f++){ float xv = xb[n*1024+f*32+t]; a = fmaf(U3[f],xv,a); c = fmaf(W3[f],xv,c); }
    rhs_t[idx]=a; xw3[idx]=c;
  }
  __syncthreads();
  for (int idx=tid; idx<704; idx+=256){
    int t = idx/22, n2 = idx - t*22; float a=0.f;
    for (int f=0;f<32;f++) a = fmaf(xu1[f*32+t], U2[f*22+n2], a);
    lhs_t[idx]=a;
  }
  __syncthreads();
  for (int idx=tid; idx<1024; idx+=256){
    int s = idx>>5, u = idx&31; float p=0.f;
    for (int n=0;n<22;n++) p = fmaf(lhs_t[s*22+n], rhs_t[n*32+u], p);
    sigp[idx] = sigm(p + be[idx]);
  }
  __syncthreads();
  for (int idx=tid; idx<1024; idx+=256){
    int t = idx>>5, u = idx&31; float a=0.f;
    for (int s2=0;s2<32;s2++) a = fmaf(Ve[t*32+s2], sigp[s2*32+u], a);
    Em[idx]=a;
  }
  __syncthreads();
  if (tid<32){
    int u=tid; float mx=-1e30f;
    for (int t=0;t<32;t++) mx = fmaxf(mx, Em[t*32+u]);
    float s=0.f; for (int t=0;t<32;t++) s += expf(Em[t*32+u]-mx);
    float inv = 1.f/s;
    for (int t=0;t<32;t++) sm[t*32+u] = expf(Em[t*32+u]-mx)*inv;
  }
  __syncthreads();
  if (tid<32){ float a=0.f; for (int t2=0;t2<32;t2++) a = fmaf(sm[tid*32+t2], W1[t2], a); w1e[tid]=a; }
  __syncthreads();
  for (int idx=tid; idx<704; idx+=256){
    int n = idx>>5, f = idx&31; float a=0.f;
    for (int u=0;u<32;u++) a = fmaf(xb[n*1024+f*32+u], w1e[u], a);
    lhsS[idx]=a;
  }
  __syncthreads();
  for (int idx=tid; idx<704; idx+=256){
    int n = idx>>5, t = idx&31; float a=0.f;
    for (int f=0;f<32;f++) a = fmaf(lhsS[n*32+f], W2[f*32+t], a);
    lhs2[idx]=a;
  }
  for (int idx=tid; idx<704; idx+=256){
    int mm = idx>>5, t = idx&31; float a=0.f;
    for (int u=0;u<32;u++) a = fmaf(xw3[mm*32+u], sm[u*32+t], a);
    rhsS[idx]=a;
  }
  __syncthreads();
  for (int idx=tid; idx<484; idx+=256){
    int a_ = idx/22, l = idx - (idx/22)*22; float p=0.f;
    for (int t=0;t<32;t++) p = fmaf(lhs2[a_*32+t], rhsS[l*32+t], p);
    sig2[idx] = sigm(p + bs[idx]);
  }
  __syncthreads();
  for (int idx=tid; idx<484; idx+=256){
    int n = idx/22, l = idx - (idx/22)*22; float s=0.f;
    for (int mm=0;mm<22;mm++) s = fmaf(Vs[n*22+mm], sig2[mm*22+l], s);
    Sl[idx]=s;
  }
  __syncthreads();
  if (tid<22){
    int l=tid; float mx=-1e30f;
    for (int n=0;n<22;n++) mx = fmaxf(mx, Sl[n*22+l]);
    float s=0.f; for (int n=0;n<22;n++) s += expf(Sl[n*22+l]-mx);
    float inv=1.f/s;
    for (int n=0;n<22;n++) snorm[(size_t)b*484 + n*22 + l] = expf(Sl[n*22+l]-mx)*inv;
  }
}

// ---------------- Fused MFMA: cheb (scalar) + Theta GEMM (MFMA) + tconv/rconv (MFMA) + LN ----
// One block (256 thr = 4 waves) per (b,m). LDS ~15.5KB.
__global__ __launch_bounds__(256, 4) void k_fused(
    const float* __restrict__ x,
    const float* __restrict__ wsT, const float* __restrict__ snorm,
    const u16* __restrict__ thA, const u16* __restrict__ wA, const float* __restrict__ wsB,
    const float* __restrict__ lng, const float* __restrict__ lnb,
    float* __restrict__ out){
  __shared__ __align__(16) u16 GtU[32*104];   // G^T bf16 [t][kf], stride 104
  __shared__ __align__(16) u16 sgTU[34*72];   // sg^T bf16 [t+1][c], rows 0,33 = zero pads
  __shared__ __align__(16) u16 xTU[32*40];    // x[m]^T bf16 [t][f], stride 40
  __shared__ __align__(16) float ak4[22*4];   // A_k[:,m]*snorm packed [n][k(0..2), pad]
  __shared__ __align__(16) float p1[32*4];    // LN partial sums   [t][wave]
  __shared__ __align__(16) float p2[32*4];    // LN partial sumsq  [t][wave]

  int wg = blockIdx.x;
  int logical = (wg & 7)*2816 + (wg >> 3);    // chunked XCD swizzle (22528 = 8*2816)
  int b = logical/22, m = logical - b*22;
  int tid = threadIdx.x;
  const float* xb = x + (size_t)b*22528;

  if (tid < 128) sgTU[(tid>>6)*(33*72) + (tid&63)] = 0;   // zero rows 0 and 33
  if (tid < 66){
    int k = tid/22, n = tid - k*22;
    float tk = (k==0) ? ((n==m)?1.f:0.f) : wsT[(k-1)*484 + n*22 + m];
    ak4[n*4+k] = tk * snorm[(size_t)b*484 + n*22 + m];
  }
  __syncthreads();

  // ---- Phase A (scalar fp32): G[k*32+f][t] = sum_n ak[k][n] * x[n][f][t]; write G^T bf16 ----
  {
    float a0[4]={0,0,0,0}, a1[4]={0,0,0,0}, a2[4]={0,0,0,0};
    #pragma unroll 2
    for (int n=0;n<22;n++){
      float4 av = *(const float4*)&ak4[n*4];
      #pragma unroll
      for (int p=0;p<4;p++){
        float xv = xb[n*1024 + tid + p*256];
        a0[p] = fmaf(av.x, xv, a0[p]);
        a1[p] = fmaf(av.y, xv, a1[p]);
        a2[p] = fmaf(av.z, xv, a2[p]);
      }
    }
    #pragma unroll
    for (int p=0;p<4;p++){
      int idx = tid + p*256, f = idx>>5, t = idx&31;
      int base = t*104 + f;
      GtU[base]      = f2bf(a0[p]);
      GtU[base + 32] = f2bf(a1[p]);
      GtU[base + 64] = f2bf(a2[p]);
      xTU[t*40 + f]  = f2bf(xb[m*1024 + idx]);
    }
  }
  __syncthreads();

  int w = tid>>6, l = tid&63, r = l&15, g = l>>4;

  // ---- Phase B (MFMA): sg[c][t] = relu( sum_kf Theta[kf][c] * G[kf][t] ), K=96 ----
  {
    const u16* tA = thA + (size_t)(w*64 + l)*8;
    short8 a0 = *(const short8*)(tA);
    short8 a1 = *(const short8*)(tA + 2048);
    short8 a2 = *(const short8*)(tA + 4096);
    #pragma unroll
    for (int ti=0; ti<2; ++ti){
      f32x4 acc = {0.f,0.f,0.f,0.f};
      const u16* gp = GtU + (ti*16 + r)*104 + 8*g;
      acc = __builtin_amdgcn_mfma_f32_16x16x32_bf16(a0, *(const short8*)(gp),      acc, 0,0,0);
      acc = __builtin_amdgcn_mfma_f32_16x16x32_bf16(a1, *(const short8*)(gp + 32), acc, 0,0,0);
      acc = __builtin_amdgcn_mfma_f32_16x16x32_bf16(a2, *(const short8*)(gp + 64), acc, 0,0,0);
      int row = 1 + ti*16 + r, c0 = w*16 + g*4;     // D: col(t)=l&15, row(c)=4*(l>>4)+i
      unsigned u01 = (unsigned)f2bf(fmaxf(acc[0],0.f)) | ((unsigned)f2bf(fmaxf(acc[1],0.f))<<16);
      unsigned u23 = (unsigned)f2bf(fmaxf(acc[2],0.f)) | ((unsigned)f2bf(fmaxf(acc[3],0.f))<<16);
      *(unsigned*)&sgTU[row*72 + c0]     = u01;
      *(unsigned*)&sgTU[row*72 + c0 + 2] = u23;
    }
  }
  __syncthreads();

  // ---- Phase C (MFMA): y[o][t] = sum_k W[k][o]*B[k][t], K=224 (k = dt*64+c | 192+f) ----
  f32x4 acc0 = {0.f,0.f,0.f,0.f}, acc1 = {0.f,0.f,0.f,0.f};
  {
    const u16* pA = wA + (size_t)(w*64 + l)*8;
    short8 wa[7];
    #pragma unroll
    for (int ks=0; ks<7; ++ks) wa[ks] = *(const short8*)(pA + ks*2048);
    #pragma unroll
    for (int ks=0; ks<6; ++ks){
      int seg = ks>>1, colb = (ks&1)*32 + 8*g;
      const u16* q0 = sgTU + (r + seg)*72 + colb;     // B[k][t]: row = t+seg (t-1+dt shifted +1)
      acc0 = __builtin_amdgcn_mfma_f32_16x16x32_bf16(wa[ks], *(const short8*)(q0),          acc0, 0,0,0);
      acc1 = __builtin_amdgcn_mfma_f32_16x16x32_bf16(wa[ks], *(const short8*)(q0 + 16*72),  acc1, 0,0,0);
    }
    const u16* q = xTU + r*40 + 8*g;
    acc0 = __builtin_amdgcn_mfma_f32_16x16x32_bf16(wa[6], *(const short8*)(q),           acc0, 0,0,0);
    acc1 = __builtin_amdgcn_mfma_f32_16x16x32_bf16(wa[6], *(const short8*)(q + 16*40),   acc1, 0,0,0);
  }

  // ---- Epilogue: bias + relu + LayerNorm over o (64) per t, store ----
  float4 bias4 = ((const float4*)wsB)[w*4 + g];       // o0 = 16w+4g
  float bb[4] = {bias4.x, bias4.y, bias4.z, bias4.w};
  float y0[4], y1[4];
  float s10=0.f, s20=0.f, s11=0.f, s21=0.f;
  #pragma unroll
  for (int i=0;i<4;i++){
    float v0 = fmaxf(acc0[i] + bb[i], 0.f); y0[i]=v0; s10 += v0; s20 = fmaf(v0,v0,s20);
    float v1 = fmaxf(acc1[i] + bb[i], 0.f); y1[i]=v1; s11 += v1; s21 = fmaf(v1,v1,s21);
  }
  s10 += __shfl_xor(s10,16); s10 += __shfl_xor(s10,32);
  s20 += __shfl_xor(s20,16); s20 += __shfl_xor(s20,32);
  s11 += __shfl_xor(s11,16); s11 += __shfl_xor(s11,32);
  s21 += __shfl_xor(s21,16); s21 += __shfl_xor(s21,32);
  if (l < 32){
    p1[l*4 + w] = (l<16) ? s10 : s11;
    p2[l*4 + w] = (l<16) ? s20 : s21;
  }
  __syncthreads();
  float4 q1a = ((const float4*)p1)[r],      q2a = ((const float4*)p2)[r];
  float4 q1b = ((const float4*)p1)[16+r],   q2b = ((const float4*)p2)[16+r];
  float S1a = q1a.x+q1a.y+q1a.z+q1a.w, S2a = q2a.x+q2a.y+q2a.z+q2a.w;
  float S1b = q1b.x+q1b.y+q1b.z+q1b.w, S2b = q2b.x+q2b.y+q2b.z+q2b.w;
  float mu0 = S1a*(1.f/64.f), var0 = S2a*(1.f/64.f) - mu0*mu0, rs0 = rsqrtf(var0 + 1e-5f);
  float mu1 = S1b*(1.f/64.f), var1 = S2b*(1.f/64.f) - mu1*mu1, rs1 = rsqrtf(var1 + 1e-5f);
  float4 g4 = ((const float4*)lng)[w*4 + g];
  float4 b4 = ((const float4*)lnb)[w*4 + g];
  float gg[4]={g4.x,g4.y,g4.z,g4.w}, bgg[4]={b4.x,b4.y,b4.z,b4.w};
  float* ob = out + (size_t)logical*2048 + (w*16 + g*4)*32;
  #pragma unroll
  for (int i=0;i<4;i++){
    ob[i*32 + r]      = (y0[i]-mu0)*rs0*gg[i] + bgg[i];
    ob[i*32 + 16 + r] = (y1[i]-mu1)*rs1*gg[i] + bgg[i];
  }
}

extern "C" void kernel_launch(void* const* d_in, const int* in_sizes, int n_in,
                              void* d_out, int out_size, void* d_ws, size_t ws_size,
                              hipStream_t stream){
  const float* x     = (const float*)d_in[0];
  const float* U1    = (const float*)d_in[1];
  const float* U2    = (const float*)d_in[2];
  const float* U3    = (const float*)d_in[3];
  const float* be    = (const float*)d_in[4];
  const float* Ve    = (const float*)d_in[5];
  const float* W1    = (const float*)d_in[6];
  const float* W2    = (const float*)d_in[7];
  const float* W3    = (const float*)d_in[8];
  const float* bs    = (const float*)d_in[9];
  const float* Vs    = (const float*)d_in[10];
  const float* Theta = (const float*)d_in[11];
  const float* emb   = (const float*)d_in[12];
  const float* tw    = (const float*)d_in[13];
  const float* tb    = (const float*)d_in[14];
  const float* rw    = (const float*)d_in[15];
  const float* rb    = (const float*)d_in[16];
  const float* lng   = (const float*)d_in[17];
  const float* lnb   = (const float*)d_in[18];
  float* out = (float*)d_out;
  float* wsf = (float*)d_ws;
  float* wsT   = wsf;                        // 968 floats (pad to 1024)
  float* snorm = wsf + 1024;                 // 1024*484 floats
  u16*   thA   = (u16*)(wsf + 496640);       // 6144 u16 (3072 floats)
  u16*   wA    = (u16*)(wsf + 499712);       // 14336 u16 (7168 floats)
  float* wsB   = wsf + 506880;               // 64 floats

  k_supports<<<1, 512, 0, stream>>>(emb, wsT);
  k_prep<<<81, 256, 0, stream>>>(Theta, tw, tb, rw, rb, thA, wA, wsB);
  k_attn<<<1024, 256, 0, stream>>>(x, U1,U2,U3, be,Ve, W1,W2,W3, bs,Vs, snorm);
  k_fused<<<1024*22, 256, 0, stream>>>(x, wsT, snorm, thA, wA, wsB, lng, lnb, out);
}

// Round 4
// 160.611 us; speedup vs baseline: 9.0879x; 1.2408x over previous
//
#include <hip/hip_runtime.h>
#include <math.h>

// B=1024, N=22, F_IN=32, T=32, K=3, CHEV=64, TIMEF=64
// x[b,n,f,t]: b-stride 22528, n-stride 1024, f-stride 32

typedef unsigned short u16;
typedef __attribute__((ext_vector_type(8))) short short8;
typedef __attribute__((ext_vector_type(4))) float f32x4;

__device__ __forceinline__ float sigm(float v){ return 1.f/(1.f+expf(-v)); }

__device__ __forceinline__ u16 f2bf(float x){
  union { float f; unsigned u; } c; c.f = x;
  unsigned r = (c.u + 0x7fffu + ((c.u>>16)&1u)) >> 16;
  return (u16)r;
}

// ---------------- K0: Chebyshev supports ----
__global__ void k_supports(const float* __restrict__ emb, float* __restrict__ wsT){
  __shared__ float M[484];
  __shared__ float T1s[484];
  int tid = threadIdx.x;
  if (tid < 484){
    int n = tid/22, m = tid - (tid/22)*22;
    float s = 0.f;
    for (int j=0;j<22;j++) s += emb[n*22+j]*emb[m*22+j];
    M[tid] = fmaxf(s, 0.f);
  }
  __syncthreads();
  if (tid < 22){
    float mx = -1e30f;
    for (int m=0;m<22;m++) mx = fmaxf(mx, M[tid*22+m]);
    float s = 0.f;
    for (int m=0;m<22;m++) s += expf(M[tid*22+m]-mx);
    float inv = 1.f/s;
    for (int m=0;m<22;m++) T1s[tid*22+m] = expf(M[tid*22+m]-mx)*inv;
  }
  __syncthreads();
  if (tid < 484){
    int n = tid/22, m = tid - (tid/22)*22;
    float s = 0.f;
    for (int p=0;p<22;p++) s += T1s[n*22+p]*T1s[p*22+m];
    wsT[tid]      = T1s[tid];
    wsT[484+tid]  = 2.f*s - ((n==m)?1.f:0.f);
  }
}

// ---------------- K_prep: pack Theta / tconv+rconv weights into bf16 MFMA A-fragment layout ----
__global__ void k_prep(const float* __restrict__ Theta,
                       const float* __restrict__ tw, const float* __restrict__ tb,
                       const float* __restrict__ rw, const float* __restrict__ rb,
                       u16* __restrict__ thA, u16* __restrict__ wA, float* __restrict__ wsB){
  int tid = blockIdx.x*256 + threadIdx.x;
  if (tid < 6144){
    int j = tid&7, l = (tid>>3)&63, blk = tid>>9;      // blk 0..11
    int ks = blk>>2, ci = blk&3, r = l&15, g = l>>4;
    int kf = 32*ks + 8*g + j, c = 16*ci + r;
    thA[tid] = f2bf(Theta[kf*64 + c]);
  } else if (tid < 20480){
    int e = tid - 6144;
    int j = e&7, l = (e>>3)&63, blk = e>>9;            // blk 0..27
    int ks = blk>>2, oi = blk&3, r = l&15, g = l>>4;
    int k = 32*ks + 8*g + j, o = 16*oi + r;
    float v = (k < 192) ? tw[o*192 + (k&63)*3 + (k>>6)] : rw[o*32 + (k-192)];
    wA[e] = f2bf(v);
  } else if (tid < 20544){
    int o = tid - 20480; wsB[o] = tb[o] + rb[o];
  }
}

// ---------------- K12: temporal + spatial attention -> S_norm (512 threads) ----
__global__ __launch_bounds__(512) void k_attn(
    const float* __restrict__ x,
    const float* __restrict__ U1, const float* __restrict__ U2, const float* __restrict__ U3,
    const float* __restrict__ be, const float* __restrict__ Ve,
    const float* __restrict__ W1, const float* __restrict__ W2, const float* __restrict__ W3,
    const float* __restrict__ bs, const float* __restrict__ Vs,
    float* __restrict__ snorm){
  int b = blockIdx.x, tid = threadIdx.x;
  const float* xb = x + (size_t)b*22528;
  __shared__ float xu1[1024];
  __shared__ float rhs_t[704];
  __shared__ float lhs_t[704];
  __shared__ float sigp[1024];
  __shared__ float Em[1024];
  __shared__ float sm[1024];
  __shared__ float w1e[32];
  __shared__ float xw3[704];
  __shared__ float lhsS[704];
  __shared__ float lhs2[704];
  __shared__ float rhsS[704];
  __shared__ float sig2[484];
  __shared__ float Sl[484];

  for (int idx=tid; idx<1024; idx+=512){
    float a=0.f;
    for (int n=0;n<22;n++) a = fmaf(xb[n*1024 + idx], U1[n], a);
    xu1[idx]=a;
  }
  for (int idx=tid; idx<704; idx+=512){
    int n = idx>>5, t = idx&31; float a=0.f, c=0.f;
    for (int f=0;f<32;f++){ float xv = xb[n*1024+f*32+t]; a = fmaf(U3[f],xv,a); c = fmaf(W3[f],xv,c); }
    rhs_t[idx]=a; xw3[idx]=c;
  }
  __syncthreads();
  for (int idx=tid; idx<704; idx+=512){
    int t = idx/22, n2 = idx - t*22; float a=0.f;
    for (int f=0;f<32;f++) a = fmaf(xu1[f*32+t], U2[f*22+n2], a);
    lhs_t[idx]=a;
  }
  __syncthreads();
  for (int idx=tid; idx<1024; idx+=512){
    int s = idx>>5, u = idx&31; float p=0.f;
    for (int n=0;n<22;n++) p = fmaf(lhs_t[s*22+n], rhs_t[n*32+u], p);
    sigp[idx] = sigm(p + be[idx]);
  }
  __syncthreads();
  for (int idx=tid; idx<1024; idx+=512){
    int t = idx>>5, u = idx&31; float a=0.f;
    for (int s2=0;s2<32;s2++) a = fmaf(Ve[t*32+s2], sigp[s2*32+u], a);
    Em[idx]=a;
  }
  __syncthreads();
  if (tid<32){
    int u=tid; float mx=-1e30f;
    for (int t=0;t<32;t++) mx = fmaxf(mx, Em[t*32+u]);
    float s=0.f; for (int t=0;t<32;t++) s += expf(Em[t*32+u]-mx);
    float inv = 1.f/s;
    for (int t=0;t<32;t++) sm[t*32+u] = expf(Em[t*32+u]-mx)*inv;
  }
  __syncthreads();
  if (tid<32){ float a=0.f; for (int t2=0;t2<32;t2++) a = fmaf(sm[tid*32+t2], W1[t2], a); w1e[tid]=a; }
  __syncthreads();
  for (int idx=tid; idx<704; idx+=512){
    int n = idx>>5, f = idx&31; float a=0.f;
    for (int u=0;u<32;u++) a = fmaf(xb[n*1024+f*32+u], w1e[u], a);
    lhsS[idx]=a;
  }
  __syncthreads();
  for (int idx=tid; idx<704; idx+=512){
    int n = idx>>5, t = idx&31; float a=0.f;
    for (int f=0;f<32;f++) a = fmaf(lhsS[n*32+f], W2[f*32+t], a);
    lhs2[idx]=a;
  }
  for (int idx=tid; idx<704; idx+=512){
    int mm = idx>>5, t = idx&31; float a=0.f;
    for (int u=0;u<32;u++) a = fmaf(xw3[mm*32+u], sm[u*32+t], a);
    rhsS[idx]=a;
  }
  __syncthreads();
  for (int idx=tid; idx<484; idx+=512){
    int a_ = idx/22, l = idx - (idx/22)*22; float p=0.f;
    for (int t=0;t<32;t++) p = fmaf(lhs2[a_*32+t], rhsS[l*32+t], p);
    sig2[idx] = sigm(p + bs[idx]);
  }
  __syncthreads();
  for (int idx=tid; idx<484; idx+=512){
    int n = idx/22, l = idx - (idx/22)*22; float s=0.f;
    for (int mm=0;mm<22;mm++) s = fmaf(Vs[n*22+mm], sig2[mm*22+l], s);
    Sl[idx]=s;
  }
  __syncthreads();
  if (tid<22){
    int l=tid; float mx=-1e30f;
    for (int n=0;n<22;n++) mx = fmaxf(mx, Sl[n*22+l]);
    float s=0.f; for (int n=0;n<22;n++) s += expf(Sl[n*22+l]-mx);
    float inv=1.f/s;
    for (int n=0;n<22;n++) snorm[(size_t)b*484 + n*22 + l] = expf(Sl[n*22+l]-mx)*inv;
  }
}

__device__ __forceinline__ void fma4(float4& a, float c, const float4& v){
  a.x = fmaf(c, v.x, a.x); a.y = fmaf(c, v.y, a.y);
  a.z = fmaf(c, v.z, a.z); a.w = fmaf(c, v.w, a.w);
}

// ---------------- Fused m-pair: cheb(k=1,2 scalar; k=0 folded) + Theta MFMA + conv MFMA + LN ----
__global__ __launch_bounds__(256, 6) void k_fused(
    const float* __restrict__ x,
    const float* __restrict__ wsT, const float* __restrict__ snorm,
    const u16* __restrict__ thA, const u16* __restrict__ wA, const float* __restrict__ wsB,
    const float* __restrict__ lng, const float* __restrict__ lnb,
    float* __restrict__ out){
  __shared__ __align__(16) u16 GtU[2][32*72];   // G^T bf16 [t][k1:0..31 | k2:32..63], stride 72
  __shared__ __align__(16) u16 sgTU[2][34*72];  // sg^T bf16 [t+1][c], rows 0,33 zero
  __shared__ __align__(16) u16 xTU[2][32*40];   // x[m]^T bf16 [t][f], stride 40
  __shared__ __align__(16) float akL[2][2][22]; // [mi][k-1][n]
  __shared__ float smm[2];

  int wg = blockIdx.x;
  int logical = (wg & 7)*1408 + (wg >> 3);      // 11264 = 8*1408 XCD swizzle
  int b = logical/11, mp = logical - b*11;
  int m0 = mp*2;
  int tid = threadIdx.x;
  const float* xb = x + (size_t)b*22528;

  if (tid < 128){                                // zero sg pad rows 0, 33
    int mi = tid>>6, r6 = tid&63;
    int row = (r6>>5) ? 33 : 0, c2 = r6&31;
    *(unsigned*)&sgTU[mi][row*72 + c2*2] = 0u;
  }
  if (tid < 88){
    int mi = tid/44, rem = tid - mi*44;
    int k1 = rem/22, n = rem - k1*22;
    int m = m0 + mi;
    akL[mi][k1][n] = wsT[k1*484 + n*22 + m] * snorm[(size_t)b*484 + n*22 + m];
  }
  if (tid < 2) smm[tid] = snorm[(size_t)b*484 + (m0+tid)*23];
  __syncthreads();

  // ---- Phase A: G[k][f][t] = sum_n akL[k][n]*x[n][f][t], k=1,2 only; + xTU tiles ----
  {
    float4 acc[2][2];
    #pragma unroll
    for (int a=0;a<2;a++){ acc[a][0]=float4{0,0,0,0}; acc[a][1]=float4{0,0,0,0}; }
    const float4* x4 = (const float4*)xb;
    #pragma unroll 2
    for (int n=0;n<22;n++){
      float4 xv = x4[n*256 + tid];
      fma4(acc[0][0], akL[0][0][n], xv);
      fma4(acc[0][1], akL[0][1][n], xv);
      fma4(acc[1][0], akL[1][0][n], xv);
      fma4(acc[1][1], akL[1][1][n], xv);
    }
    int f = tid>>3, t0 = (tid&7)*4;
    #pragma unroll
    for (int mi=0;mi<2;mi++){
      float4 xm = x4[(m0+mi)*256 + tid];
      u16* xd = &xTU[mi][0];
      xd[(t0+0)*40 + f] = f2bf(xm.x);
      xd[(t0+1)*40 + f] = f2bf(xm.y);
      xd[(t0+2)*40 + f] = f2bf(xm.z);
      xd[(t0+3)*40 + f] = f2bf(xm.w);
      #pragma unroll
      for (int k1=0;k1<2;k1++){
        float4 v = acc[mi][k1];
        u16* gd = &GtU[mi][k1*32 + f];
        gd[(t0+0)*72] = f2bf(v.x);
        gd[(t0+1)*72] = f2bf(v.y);
        gd[(t0+2)*72] = f2bf(v.z);
        gd[(t0+3)*72] = f2bf(v.w);
      }
    }
  }
  __syncthreads();

  int w = tid>>6, l = tid&63, r = l&15, g = l>>4;

  // ---- Phase B: sg[c][t] = relu( sum_{k=1,2} + smm * (Theta0^T x[m]) ), per m ----
  {
    const u16* tA = thA + (size_t)(w*64 + l)*8;
    short8 a0 = *(const short8*)(tA);
    short8 a1 = *(const short8*)(tA + 2048);
    short8 a2 = *(const short8*)(tA + 4096);
    #pragma unroll
    for (int mi=0;mi<2;mi++){
      float sm_ = smm[mi];
      #pragma unroll
      for (int ti=0; ti<2; ++ti){
        f32x4 a12 = {0.f,0.f,0.f,0.f}, ax = {0.f,0.f,0.f,0.f};
        const u16* gp = &GtU[mi][(ti*16 + r)*72 + 8*g];
        a12 = __builtin_amdgcn_mfma_f32_16x16x32_bf16(a1, *(const short8*)(gp),      a12, 0,0,0);
        a12 = __builtin_amdgcn_mfma_f32_16x16x32_bf16(a2, *(const short8*)(gp + 32), a12, 0,0,0);
        const u16* xp = &xTU[mi][(ti*16 + r)*40 + 8*g];
        ax  = __builtin_amdgcn_mfma_f32_16x16x32_bf16(a0, *(const short8*)(xp),      ax,  0,0,0);
        int row = 1 + ti*16 + r, c0 = w*16 + g*4;
        float v0 = fmaxf(fmaf(sm_, ax[0], a12[0]), 0.f);
        float v1 = fmaxf(fmaf(sm_, ax[1], a12[1]), 0.f);
        float v2 = fmaxf(fmaf(sm_, ax[2], a12[2]), 0.f);
        float v3 = fmaxf(fmaf(sm_, ax[3], a12[3]), 0.f);
        unsigned u01 = (unsigned)f2bf(v0) | ((unsigned)f2bf(v1)<<16);
        unsigned u23 = (unsigned)f2bf(v2) | ((unsigned)f2bf(v3)<<16);
        *(unsigned*)&sgTU[mi][row*72 + c0]     = u01;
        *(unsigned*)&sgTU[mi][row*72 + c0 + 2] = u23;
      }
    }
  }
  __syncthreads();

  // ---- Phase C: y[o][t] = sum_k W[k][o]*B[k][t], K=224, per m ----
  f32x4 acc[2][2];
  acc[0][0]=f32x4{0,0,0,0}; acc[0][1]=f32x4{0,0,0,0};
  acc[1][0]=f32x4{0,0,0,0}; acc[1][1]=f32x4{0,0,0,0};
  {
    const u16* pA = wA + (size_t)(w*64 + l)*8;
    #pragma unroll
    for (int ks=0; ks<6; ++ks){
      short8 wk = *(const short8*)(pA + ks*2048);
      int seg = ks>>1, colb = (ks&1)*32 + 8*g;
      #pragma unroll
      for (int mi=0;mi<2;mi++){
        const u16* q0 = &sgTU[mi][(r + seg)*72 + colb];
        acc[mi][0] = __builtin_amdgcn_mfma_f32_16x16x32_bf16(wk, *(const short8*)(q0),         acc[mi][0], 0,0,0);
        acc[mi][1] = __builtin_amdgcn_mfma_f32_16x16x32_bf16(wk, *(const short8*)(q0 + 16*72), acc[mi][1], 0,0,0);
      }
    }
    short8 wk = *(const short8*)(pA + 6*2048);
    #pragma unroll
    for (int mi=0;mi<2;mi++){
      const u16* q = &xTU[mi][r*40 + 8*g];
      acc[mi][0] = __builtin_amdgcn_mfma_f32_16x16x32_bf16(wk, *(const short8*)(q),         acc[mi][0], 0,0,0);
      acc[mi][1] = __builtin_amdgcn_mfma_f32_16x16x32_bf16(wk, *(const short8*)(q + 16*40), acc[mi][1], 0,0,0);
    }
  }

  // ---- Epilogue: bias + relu + LN over o per t, both m ----
  float4 bias4 = ((const float4*)wsB)[w*4 + g];
  float bb[4] = {bias4.x, bias4.y, bias4.z, bias4.w};
  float y[2][2][4];
  float s1[2][2] = {{0.f,0.f},{0.f,0.f}}, s2[2][2] = {{0.f,0.f},{0.f,0.f}};
  #pragma unroll
  for (int mi=0;mi<2;mi++){
    #pragma unroll
    for (int h=0;h<2;h++){
      #pragma unroll
      for (int i=0;i<4;i++){
        float v = fmaxf(acc[mi][h][i] + bb[i], 0.f);
        y[mi][h][i] = v;
        s1[mi][h] += v;
        s2[mi][h] = fmaf(v, v, s2[mi][h]);
      }
      s1[mi][h] += __shfl_xor(s1[mi][h],16); s1[mi][h] += __shfl_xor(s1[mi][h],32);
      s2[mi][h] += __shfl_xor(s2[mi][h],16); s2[mi][h] += __shfl_xor(s2[mi][h],32);
    }
  }
  float* p1 = (float*)&GtU[0][0];     // overlay: [mi*32+t][4w] sums, then sumsq at +256
  float* p2 = p1 + 256;
  if (l < 16){
    #pragma unroll
    for (int mi=0;mi<2;mi++){
      p1[(mi*32 + l)*4 + w]      = s1[mi][0];
      p1[(mi*32 + 16 + l)*4 + w] = s1[mi][1];
      p2[(mi*32 + l)*4 + w]      = s2[mi][0];
      p2[(mi*32 + 16 + l)*4 + w] = s2[mi][1];
    }
  }
  __syncthreads();
  float4 g4 = ((const float4*)lng)[w*4 + g];
  float4 b4 = ((const float4*)lnb)[w*4 + g];
  float gg[4]={g4.x,g4.y,g4.z,g4.w}, bgg[4]={b4.x,b4.y,b4.z,b4.w};
  #pragma unroll
  for (int mi=0;mi<2;mi++){
    float4 q1a = ((const float4*)p1)[mi*32 + r],      q2a = ((const float4*)p2)[mi*32 + r];
    float4 q1b = ((const float4*)p1)[mi*32 + 16 + r], q2b = ((const float4*)p2)[mi*32 + 16 + r];
    float S1a = q1a.x+q1a.y+q1a.z+q1a.w, S2a = q2a.x+q2a.y+q2a.z+q2a.w;
    float S1b = q1b.x+q1b.y+q1b.z+q1b.w, S2b = q2b.x+q2b.y+q2b.z+q2b.w;
    float mu0 = S1a*(1.f/64.f), var0 = S2a*(1.f/64.f) - mu0*mu0, rs0 = rsqrtf(var0 + 1e-5f);
    float mu1 = S1b*(1.f/64.f), var1 = S2b*(1.f/64.f) - mu1*mu1, rs1 = rsqrtf(var1 + 1e-5f);
    float* ob = out + ((size_t)(b*22 + m0 + mi)*64 + (w*16 + g*4))*32;
    #pragma unroll
    for (int i=0;i<4;i++){
      ob[i*32 + r]      = (y[mi][0][i]-mu0)*rs0*gg[i] + bgg[i];
      ob[i*32 + 16 + r] = (y[mi][1][i]-mu1)*rs1*gg[i] + bgg[i];
    }
  }
}

extern "C" void kernel_launch(void* const* d_in, const int* in_sizes, int n_in,
                              void* d_out, int out_size, void* d_ws, size_t ws_size,
                              hipStream_t stream){
  const float* x     = (const float*)d_in[0];
  const float* U1    = (const float*)d_in[1];
  const float* U2    = (const float*)d_in[2];
  const float* U3    = (const float*)d_in[3];
  const float* be    = (const float*)d_in[4];
  const float* Ve    = (const float*)d_in[5];
  const float* W1    = (const float*)d_in[6];
  const float* W2    = (const float*)d_in[7];
  const float* W3    = (const float*)d_in[8];
  const float* bs    = (const float*)d_in[9];
  const float* Vs    = (const float*)d_in[10];
  const float* Theta = (const float*)d_in[11];
  const float* emb   = (const float*)d_in[12];
  const float* tw    = (const float*)d_in[13];
  const float* tb    = (const float*)d_in[14];
  const float* rw    = (const float*)d_in[15];
  const float* rb    = (const float*)d_in[16];
  const float* lng   = (const float*)d_in[17];
  const float* lnb   = (const float*)d_in[18];
  float* out = (float*)d_out;
  float* wsf = (float*)d_ws;
  float* wsT   = wsf;                        // 968 floats (pad to 1024)
  float* snorm = wsf + 1024;                 // 1024*484 floats
  u16*   thA   = (u16*)(wsf + 496640);       // 6144 u16
  u16*   wA    = (u16*)(wsf + 499712);       // 14336 u16
  float* wsB   = wsf + 506880;               // 64 floats

  k_supports<<<1, 512, 0, stream>>>(emb, wsT);
  k_prep<<<81, 256, 0, stream>>>(Theta, tw, tb, rw, rb, thA, wA, wsB);
  k_attn<<<1024, 512, 0, stream>>>(x, U1,U2,U3, be,Ve, W1,W2,W3, bs,Vs, snorm);
  k_fused<<<1024*11, 256, 0, stream>>>(x, wsT, snorm, thA, wA, wsB, lng, lnb, out);
}

// Round 5
// 155.376 us; speedup vs baseline: 9.3941x; 1.0337x over previous
//
#include <hip/hip_runtime.h>
#include <math.h>

// B=1024, N=22, F_IN=32, T=32, K=3, CHEV=64, TIMEF=64
// x[b,n,f,t]: b-stride 22528, n-stride 1024, f-stride 32

typedef unsigned short u16;
typedef __attribute__((ext_vector_type(8))) short short8;
typedef __attribute__((ext_vector_type(4))) float f32x4;
typedef __attribute__((ext_vector_type(2))) float f32x2;

__device__ __forceinline__ float sigm(float v){ return 1.f/(1.f+expf(-v)); }

__device__ __forceinline__ u16 f2bf(float x){
  union { float f; unsigned u; } c; c.f = x;
  unsigned r = (c.u + 0x7fffu + ((c.u>>16)&1u)) >> 16;
  return (u16)r;
}

// ---------------- K_prep (blocks 0..80) + Chebyshev supports (block 81) ----------------
__global__ void k_sup_prep(const float* __restrict__ emb, float* __restrict__ wsT,
                           const float* __restrict__ Theta,
                           const float* __restrict__ tw, const float* __restrict__ tb,
                           const float* __restrict__ rw, const float* __restrict__ rb,
                           u16* __restrict__ thA, u16* __restrict__ wA, float* __restrict__ wsB){
  if (blockIdx.x < 81){
    int tid = blockIdx.x*256 + threadIdx.x;
    if (tid < 6144){
      int j = tid&7, l = (tid>>3)&63, blk = tid>>9;      // blk 0..11
      int ks = blk>>2, ci = blk&3, r = l&15, g = l>>4;
      int kf = 32*ks + 8*g + j, c = 16*ci + r;
      thA[tid] = f2bf(Theta[kf*64 + c]);
    } else if (tid < 20480){
      int e = tid - 6144;
      int j = e&7, l = (e>>3)&63, blk = e>>9;            // blk 0..27
      int ks = blk>>2, oi = blk&3, r = l&15, g = l>>4;
      int k = 32*ks + 8*g + j, o = 16*oi + r;
      float v = (k < 192) ? tw[o*192 + (k&63)*3 + (k>>6)] : rw[o*32 + (k-192)];
      wA[e] = f2bf(v);
    } else if (tid < 20544){
      int o = tid - 20480; wsB[o] = tb[o] + rb[o];
    }
    return;
  }
  // block 81: supports
  __shared__ float M[484];
  __shared__ float T1s[484];
  int tid = threadIdx.x;
  for (int idx=tid; idx<484; idx+=256){
    int n = idx/22, m = idx - (idx/22)*22;
    float s = 0.f;
    for (int j=0;j<22;j++) s += emb[n*22+j]*emb[m*22+j];
    M[idx] = fmaxf(s, 0.f);
  }
  __syncthreads();
  if (tid < 22){
    float mx = -1e30f;
    for (int m=0;m<22;m++) mx = fmaxf(mx, M[tid*22+m]);
    float s = 0.f;
    for (int m=0;m<22;m++) s += expf(M[tid*22+m]-mx);
    float inv = 1.f/s;
    for (int m=0;m<22;m++) T1s[tid*22+m] = expf(M[tid*22+m]-mx)*inv;
  }
  __syncthreads();
  for (int idx=tid; idx<484; idx+=256){
    int n = idx/22, m = idx - (idx/22)*22;
    float s = 0.f;
    for (int p=0;p<22;p++) s += T1s[n*22+p]*T1s[p*22+m];
    wsT[idx]      = T1s[idx];
    wsT[484+idx]  = 2.f*s - ((n==m)?1.f:0.f);
  }
}

// ---------------- K12: temporal + spatial attention -> S_norm (512 threads) ----
__global__ __launch_bounds__(512) void k_attn(
    const float* __restrict__ x,
    const float* __restrict__ U1, const float* __restrict__ U2, const float* __restrict__ U3,
    const float* __restrict__ be, const float* __restrict__ Ve,
    const float* __restrict__ W1, const float* __restrict__ W2, const float* __restrict__ W3,
    const float* __restrict__ bs, const float* __restrict__ Vs,
    float* __restrict__ snorm){
  int b = blockIdx.x, tid = threadIdx.x;
  const float* xb = x + (size_t)b*22528;
  __shared__ float xu1[1024];
  __shared__ float rhs_t[704];
  __shared__ float lhs_t[704];
  __shared__ float sigp[1024];
  __shared__ float Em[1024];
  __shared__ float sm[1024];
  __shared__ float w1e[32];
  __shared__ float xw3[704];
  __shared__ float lhsS[704];
  __shared__ float lhs2[704];
  __shared__ float rhsS[704];
  __shared__ float sig2[484];
  __shared__ float Sl[484];

  for (int idx=tid; idx<1024; idx+=512){
    float a=0.f;
    for (int n=0;n<22;n++) a = fmaf(xb[n*1024 + idx], U1[n], a);
    xu1[idx]=a;
  }
  for (int idx=tid; idx<704; idx+=512){
    int n = idx>>5, t = idx&31; float a=0.f, c=0.f;
    for (int f=0;f<32;f++){ float xv = xb[n*1024+f*32+t]; a = fmaf(U3[f],xv,a); c = fmaf(W3[f],xv,c); }
    rhs_t[idx]=a; xw3[idx]=c;
  }
  __syncthreads();
  for (int idx=tid; idx<704; idx+=512){
    int t = idx/22, n2 = idx - t*22; float a=0.f;
    for (int f=0;f<32;f++) a = fmaf(xu1[f*32+t], U2[f*22+n2], a);
    lhs_t[idx]=a;
  }
  __syncthreads();
  for (int idx=tid; idx<1024; idx+=512){
    int s = idx>>5, u = idx&31; float p=0.f;
    for (int n=0;n<22;n++) p = fmaf(lhs_t[s*22+n], rhs_t[n*32+u], p);
    sigp[idx] = sigm(p + be[idx]);
  }
  __syncthreads();
  for (int idx=tid; idx<1024; idx+=512){
    int t = idx>>5, u = idx&31; float a=0.f;
    for (int s2=0;s2<32;s2++) a = fmaf(Ve[t*32+s2], sigp[s2*32+u], a);
    Em[idx]=a;
  }
  __syncthreads();
  // ---- temporal softmax over t (axis=1), all 512 threads: u=tid>>4, th=tid&15 ----
  {
    int u = tid>>4, th = tid&15;
    float e0 = Em[(2*th)*32 + u], e1 = Em[(2*th+1)*32 + u];
    float mx = fmaxf(e0, e1);
    #pragma unroll
    for (int mask=1; mask<16; mask<<=1) mx = fmaxf(mx, __shfl_xor(mx, mask));
    float x0 = expf(e0-mx), x1 = expf(e1-mx);
    float s = x0 + x1;
    #pragma unroll
    for (int mask=1; mask<16; mask<<=1) s += __shfl_xor(s, mask);
    float inv = 1.f/s;
    sm[(2*th)*32 + u]   = x0*inv;
    sm[(2*th+1)*32 + u] = x1*inv;
  }
  __syncthreads();
  {
    int u = tid>>4, th = tid&15;
    float pw = fmaf(sm[u*32 + 2*th], W1[2*th], sm[u*32 + 2*th+1]*W1[2*th+1]);
    #pragma unroll
    for (int mask=1; mask<16; mask<<=1) pw += __shfl_xor(pw, mask);
    if (th==0) w1e[u] = pw;
  }
  __syncthreads();
  for (int idx=tid; idx<704; idx+=512){
    int n = idx>>5, f = idx&31; float a=0.f;
    for (int u=0;u<32;u++) a = fmaf(xb[n*1024+f*32+u], w1e[u], a);
    lhsS[idx]=a;
  }
  __syncthreads();
  for (int idx=tid; idx<704; idx+=512){
    int n = idx>>5, t = idx&31; float a=0.f;
    for (int f=0;f<32;f++) a = fmaf(lhsS[n*32+f], W2[f*32+t], a);
    lhs2[idx]=a;
  }
  for (int idx=tid; idx<704; idx+=512){
    int mm = idx>>5, t = idx&31; float a=0.f;
    for (int u=0;u<32;u++) a = fmaf(xw3[mm*32+u], sm[u*32+t], a);
    rhsS[idx]=a;
  }
  __syncthreads();
  for (int idx=tid; idx<484; idx+=512){
    int a_ = idx/22, l = idx - (idx/22)*22; float p=0.f;
    for (int t=0;t<32;t++) p = fmaf(lhs2[a_*32+t], rhsS[l*32+t], p);
    sig2[idx] = sigm(p + bs[idx]);
  }
  __syncthreads();
  for (int idx=tid; idx<484; idx+=512){
    int n = idx/22, l = idx - (idx/22)*22; float s=0.f;
    for (int mm=0;mm<22;mm++) s = fmaf(Vs[n*22+mm], sig2[mm*22+l], s);
    Sl[idx]=s;
  }
  __syncthreads();
  // ---- spatial softmax over n (axis=1), 32-lane groups per l ----
  {
    int grp = tid>>5, nn = tid&31;
    for (int l = grp; l < 22; l += 16){
      float v = (nn<22) ? Sl[nn*22 + l] : -1e30f;
      float mx = v;
      #pragma unroll
      for (int mask=1; mask<32; mask<<=1) mx = fmaxf(mx, __shfl_xor(mx, mask));
      float e = (nn<22) ? expf(v-mx) : 0.f;
      float s = e;
      #pragma unroll
      for (int mask=1; mask<32; mask<<=1) s += __shfl_xor(s, mask);
      if (nn<22) snorm[(size_t)b*484 + nn*22 + l] = e/s;
    }
  }
}

// ---------------- Fused m-pair: cheb(k=1,2 pk-fma; k=0 folded) + Theta MFMA + conv MFMA + LN ----
__global__ __launch_bounds__(256, 6) void k_fused(
    const float* __restrict__ x,
    const float* __restrict__ wsT, const float* __restrict__ snorm,
    const u16* __restrict__ thA, const u16* __restrict__ wA, const float* __restrict__ wsB,
    const float* __restrict__ lng, const float* __restrict__ lnb,
    float* __restrict__ out){
  __shared__ __align__(16) u16 GtU[2][32*72];   // G^T bf16 [t][k1:0..31 | k2:32..63], stride 72
  __shared__ __align__(16) u16 sgTU[2][34*72];  // sg^T bf16 [t+1][c], rows 0,33 zero
  __shared__ __align__(16) u16 xTU[2][32*40];   // x[m]^T bf16 [t][f], stride 40
  __shared__ __align__(16) float akL[2][2][22]; // [mi][k-1][n]
  __shared__ float smm[2];

  int wg = blockIdx.x;
  int logical = (wg & 7)*1408 + (wg >> 3);      // 11264 = 8*1408 XCD swizzle
  int b = logical/11, mp = logical - b*11;
  int m0 = mp*2;
  int tid = threadIdx.x;
  const float* xb = x + (size_t)b*22528;

  if (tid < 128){                                // zero sg pad rows 0, 33
    int mi = tid>>6, r6 = tid&63;
    int row = (r6>>5) ? 33 : 0, c2 = r6&31;
    *(unsigned*)&sgTU[mi][row*72 + c2*2] = 0u;
  }
  if (tid < 88){
    int mi = tid/44, rem = tid - mi*44;
    int k1 = rem/22, n = rem - k1*22;
    int m = m0 + mi;
    akL[mi][k1][n] = wsT[k1*484 + n*22 + m] * snorm[(size_t)b*484 + n*22 + m];
  }
  if (tid < 2) smm[tid] = snorm[(size_t)b*484 + (m0+tid)*23];
  __syncthreads();

  // ---- Phase A: G[k][f][t] = sum_n akL[k][n]*x[n][f][t], k=1,2 only; + xTU tiles ----
  {
    f32x2 acc[2][2][2];   // [mi][k1][half]
    #pragma unroll
    for (int a=0;a<2;a++)
      #pragma unroll
      for (int k1=0;k1<2;k1++){ acc[a][k1][0]=f32x2{0,0}; acc[a][k1][1]=f32x2{0,0}; }
    const float4* x4 = (const float4*)xb;
    #pragma unroll 2
    for (int n=0;n<22;n++){
      float4 xv = x4[n*256 + tid];
      f32x2 xlo = {xv.x, xv.y}, xhi = {xv.z, xv.w};
      #pragma unroll
      for (int mi=0;mi<2;mi++){
        #pragma unroll
        for (int k1=0;k1<2;k1++){
          float a = akL[mi][k1][n];
          f32x2 av = {a, a};
          acc[mi][k1][0] = __builtin_elementwise_fma(av, xlo, acc[mi][k1][0]);
          acc[mi][k1][1] = __builtin_elementwise_fma(av, xhi, acc[mi][k1][1]);
        }
      }
    }
    int f = tid>>3, t0 = (tid&7)*4;
    #pragma unroll
    for (int mi=0;mi<2;mi++){
      float4 xm = ((const float4*)xb)[(m0+mi)*256 + tid];
      u16* xd = &xTU[mi][0];
      xd[(t0+0)*40 + f] = f2bf(xm.x);
      xd[(t0+1)*40 + f] = f2bf(xm.y);
      xd[(t0+2)*40 + f] = f2bf(xm.z);
      xd[(t0+3)*40 + f] = f2bf(xm.w);
      #pragma unroll
      for (int k1=0;k1<2;k1++){
        u16* gd = &GtU[mi][k1*32 + f];
        gd[(t0+0)*72] = f2bf(acc[mi][k1][0][0]);
        gd[(t0+1)*72] = f2bf(acc[mi][k1][0][1]);
        gd[(t0+2)*72] = f2bf(acc[mi][k1][1][0]);
        gd[(t0+3)*72] = f2bf(acc[mi][k1][1][1]);
      }
    }
  }
  __syncthreads();

  int w = tid>>6, l = tid&63, r = l&15, g = l>>4;

  // ---- Phase B: sg[c][t] = relu( sum_{k=1,2} + smm * (Theta0^T x[m]) ), per m ----
  {
    const u16* tA = thA + (size_t)(w*64 + l)*8;
    short8 a0 = *(const short8*)(tA);
    short8 a1 = *(const short8*)(tA + 2048);
    short8 a2 = *(const short8*)(tA + 4096);
    #pragma unroll
    for (int mi=0;mi<2;mi++){
      float sm_ = smm[mi];
      #pragma unroll
      for (int ti=0; ti<2; ++ti){
        f32x4 a12 = {0.f,0.f,0.f,0.f}, ax = {0.f,0.f,0.f,0.f};
        const u16* gp = &GtU[mi][(ti*16 + r)*72 + 8*g];
        a12 = __builtin_amdgcn_mfma_f32_16x16x32_bf16(a1, *(const short8*)(gp),      a12, 0,0,0);
        a12 = __builtin_amdgcn_mfma_f32_16x16x32_bf16(a2, *(const short8*)(gp + 32), a12, 0,0,0);
        const u16* xp = &xTU[mi][(ti*16 + r)*40 + 8*g];
        ax  = __builtin_amdgcn_mfma_f32_16x16x32_bf16(a0, *(const short8*)(xp),      ax,  0,0,0);
        int row = 1 + ti*16 + r, c0 = w*16 + g*4;
        float v0 = fmaxf(fmaf(sm_, ax[0], a12[0]), 0.f);
        float v1 = fmaxf(fmaf(sm_, ax[1], a12[1]), 0.f);
        float v2 = fmaxf(fmaf(sm_, ax[2], a12[2]), 0.f);
        float v3 = fmaxf(fmaf(sm_, ax[3], a12[3]), 0.f);
        unsigned u01 = (unsigned)f2bf(v0) | ((unsigned)f2bf(v1)<<16);
        unsigned u23 = (unsigned)f2bf(v2) | ((unsigned)f2bf(v3)<<16);
        *(unsigned*)&sgTU[mi][row*72 + c0]     = u01;
        *(unsigned*)&sgTU[mi][row*72 + c0 + 2] = u23;
      }
    }
  }
  __syncthreads();

  // ---- Phase C: y[o][t] = sum_k W[k][o]*B[k][t], K=224, per m ----
  f32x4 acc[2][2];
  acc[0][0]=f32x4{0,0,0,0}; acc[0][1]=f32x4{0,0,0,0};
  acc[1][0]=f32x4{0,0,0,0}; acc[1][1]=f32x4{0,0,0,0};
  {
    const u16* pA = wA + (size_t)(w*64 + l)*8;
    #pragma unroll
    for (int ks=0; ks<6; ++ks){
      short8 wk = *(const short8*)(pA + ks*2048);
      int seg = ks>>1, colb = (ks&1)*32 + 8*g;
      #pragma unroll
      for (int mi=0;mi<2;mi++){
        const u16* q0 = &sgTU[mi][(r + seg)*72 + colb];
        acc[mi][0] = __builtin_amdgcn_mfma_f32_16x16x32_bf16(wk, *(const short8*)(q0),         acc[mi][0], 0,0,0);
        acc[mi][1] = __builtin_amdgcn_mfma_f32_16x16x32_bf16(wk, *(const short8*)(q0 + 16*72), acc[mi][1], 0,0,0);
      }
    }
    short8 wk = *(const short8*)(pA + 6*2048);
    #pragma unroll
    for (int mi=0;mi<2;mi++){
      const u16* q = &xTU[mi][r*40 + 8*g];
      acc[mi][0] = __builtin_amdgcn_mfma_f32_16x16x32_bf16(wk, *(const short8*)(q),         acc[mi][0], 0,0,0);
      acc[mi][1] = __builtin_amdgcn_mfma_f32_16x16x32_bf16(wk, *(const short8*)(q + 16*40), acc[mi][1], 0,0,0);
    }
  }

  // ---- Epilogue: bias + relu + LN over o per t, both m ----
  float4 bias4 = ((const float4*)wsB)[w*4 + g];
  float bb[4] = {bias4.x, bias4.y, bias4.z, bias4.w};
  float y[2][2][4];
  float s1[2][2] = {{0.f,0.f},{0.f,0.f}}, s2[2][2] = {{0.f,0.f},{0.f,0.f}};
  #pragma unroll
  for (int mi=0;mi<2;mi++){
    #pragma unroll
    for (int h=0;h<2;h++){
      #pragma unroll
      for (int i=0;i<4;i++){
        float v = fmaxf(acc[mi][h][i] + bb[i], 0.f);
        y[mi][h][i] = v;
        s1[mi][h] += v;
        s2[mi][h] = fmaf(v, v, s2[mi][h]);
      }
      s1[mi][h] += __shfl_xor(s1[mi][h],16); s1[mi][h] += __shfl_xor(s1[mi][h],32);
      s2[mi][h] += __shfl_xor(s2[mi][h],16); s2[mi][h] += __shfl_xor(s2[mi][h],32);
    }
  }
  float* p1 = (float*)&GtU[0][0];     // overlay: [mi*32+t][4w] sums, then sumsq at +256
  float* p2 = p1 + 256;
  if (l < 16){
    #pragma unroll
    for (int mi=0;mi<2;mi++){
      p1[(mi*32 + l)*4 + w]      = s1[mi][0];
      p1[(mi*32 + 16 + l)*4 + w] = s1[mi][1];
      p2[(mi*32 + l)*4 + w]      = s2[mi][0];
      p2[(mi*32 + 16 + l)*4 + w] = s2[mi][1];
    }
  }
  __syncthreads();
  float4 g4 = ((const float4*)lng)[w*4 + g];
  float4 b4 = ((const float4*)lnb)[w*4 + g];
  float gg[4]={g4.x,g4.y,g4.z,g4.w}, bgg[4]={b4.x,b4.y,b4.z,b4.w};
  #pragma unroll
  for (int mi=0;mi<2;mi++){
    float4 q1a = ((const float4*)p1)[mi*32 + r],      q2a = ((const float4*)p2)[mi*32 + r];
    float4 q1b = ((const float4*)p1)[mi*32 + 16 + r], q2b = ((const float4*)p2)[mi*32 + 16 + r];
    float S1a = q1a.x+q1a.y+q1a.z+q1a.w, S2a = q2a.x+q2a.y+q2a.z+q2a.w;
    float S1b = q1b.x+q1b.y+q1b.z+q1b.w, S2b = q2b.x+q2b.y+q2b.z+q2b.w;
    float mu0 = S1a*(1.f/64.f), var0 = S2a*(1.f/64.f) - mu0*mu0, rs0 = rsqrtf(var0 + 1e-5f);
    float mu1 = S1b*(1.f/64.f), var1 = S2b*(1.f/64.f) - mu1*mu1, rs1 = rsqrtf(var1 + 1e-5f);
    float* ob = out + ((size_t)(b*22 + m0 + mi)*64 + (w*16 + g*4))*32;
    #pragma unroll
    for (int i=0;i<4;i++){
      ob[i*32 + r]      = (y[mi][0][i]-mu0)*rs0*gg[i] + bgg[i];
      ob[i*32 + 16 + r] = (y[mi][1][i]-mu1)*rs1*gg[i] + bgg[i];
    }
  }
}

extern "C" void kernel_launch(void* const* d_in, const int* in_sizes, int n_in,
                              void* d_out, int out_size, void* d_ws, size_t ws_size,
                              hipStream_t stream){
  const float* x     = (const float*)d_in[0];
  const float* U1    = (const float*)d_in[1];
  const float* U2    = (const float*)d_in[2];
  const float* U3    = (const float*)d_in[3];
  const float* be    = (const float*)d_in[4];
  const float* Ve    = (const float*)d_in[5];
  const float* W1    = (const float*)d_in[6];
  const float* W2    = (const float*)d_in[7];
  const float* W3    = (const float*)d_in[8];
  const float* bs    = (const float*)d_in[9];
  const float* Vs    = (const float*)d_in[10];
  const float* Theta = (const float*)d_in[11];
  const float* emb   = (const float*)d_in[12];
  const float* tw    = (const float*)d_in[13];
  const float* tb    = (const float*)d_in[14];
  const float* rw    = (const float*)d_in[15];
  const float* rb    = (const float*)d_in[16];
  const float* lng   = (const float*)d_in[17];
  const float* lnb   = (const float*)d_in[18];
  float* out = (float*)d_out;
  float* wsf = (float*)d_ws;
  float* wsT   = wsf;                        // 968 floats (pad to 1024)
  float* snorm = wsf + 1024;                 // 1024*484 floats
  u16*   thA   = (u16*)(wsf + 496640);       // 6144 u16
  u16*   wA    = (u16*)(wsf + 499712);       // 14336 u16
  float* wsB   = wsf + 506880;               // 64 floats

  k_sup_prep<<<82, 256, 0, stream>>>(emb, wsT, Theta, tw, tb, rw, rb, thA, wA, wsB);
  k_attn<<<1024, 512, 0, stream>>>(x, U1,U2,U3, be,Ve, W1,W2,W3, bs,Vs, snorm);
  k_fused<<<1024*11, 256, 0, stream>>>(x, wsT, snorm, thA, wA, wsB, lng, lnb, out);
}

// Round 6
// 152.066 us; speedup vs baseline: 9.5985x; 1.0218x over previous
//
#include <hip/hip_runtime.h>
#include <hip/hip_bf16.h>
#include <math.h>

// B=1024, N=22, F_IN=32, T=32, K=3, CHEV=64, TIMEF=64
// x[b,n,f,t]: b-stride 22528, n-stride 1024, f-stride 32

typedef unsigned short u16;
typedef __attribute__((ext_vector_type(8))) short short8;
typedef __attribute__((ext_vector_type(4))) float f32x4;
typedef __attribute__((ext_vector_type(2))) float f32x2;

__device__ __forceinline__ float sigm(float v){ return 1.f/(1.f+expf(-v)); }

__device__ __forceinline__ u16 f2bf(float x){
  __hip_bfloat16 h = __float2bfloat16(x);
  return *reinterpret_cast<u16*>(&h);
}
__device__ __forceinline__ unsigned f2bf2(float lo, float hi){
  return (unsigned)f2bf(lo) | ((unsigned)f2bf(hi) << 16);
}

// ---------------- K_prep (blocks 0..80) + Chebyshev supports (block 81) ----------------
__global__ void k_sup_prep(const float* __restrict__ emb, float* __restrict__ wsT,
                           const float* __restrict__ Theta,
                           const float* __restrict__ tw, const float* __restrict__ tb,
                           const float* __restrict__ rw, const float* __restrict__ rb,
                           u16* __restrict__ thA, u16* __restrict__ wA, float* __restrict__ wsB){
  if (blockIdx.x < 81){
    int tid = blockIdx.x*256 + threadIdx.x;
    if (tid < 6144){
      int j = tid&7, l = (tid>>3)&63, blk = tid>>9;      // blk 0..11
      int ks = blk>>2, ci = blk&3, r = l&15, g = l>>4;
      int kf = 32*ks + 8*g + j, c = 16*ci + r;
      thA[tid] = f2bf(Theta[kf*64 + c]);
    } else if (tid < 20480){
      int e = tid - 6144;
      int j = e&7, l = (e>>3)&63, blk = e>>9;            // blk 0..27
      int ks = blk>>2, oi = blk&3, r = l&15, g = l>>4;
      int k = 32*ks + 8*g + j, o = 16*oi + r;
      float v = (k < 192) ? tw[o*192 + (k&63)*3 + (k>>6)] : rw[o*32 + (k-192)];
      wA[e] = f2bf(v);
    } else if (tid < 20544){
      int o = tid - 20480; wsB[o] = tb[o] + rb[o];
    }
    return;
  }
  // block 81: supports
  __shared__ float M[484];
  __shared__ float T1s[484];
  int tid = threadIdx.x;
  for (int idx=tid; idx<484; idx+=256){
    int n = idx/22, m = idx - (idx/22)*22;
    float s = 0.f;
    for (int j=0;j<22;j++) s += emb[n*22+j]*emb[m*22+j];
    M[idx] = fmaxf(s, 0.f);
  }
  __syncthreads();
  if (tid < 22){
    float mx = -1e30f;
    for (int m=0;m<22;m++) mx = fmaxf(mx, M[tid*22+m]);
    float s = 0.f;
    for (int m=0;m<22;m++) s += expf(M[tid*22+m]-mx);
    float inv = 1.f/s;
    for (int m=0;m<22;m++) T1s[tid*22+m] = expf(M[tid*22+m]-mx)*inv;
  }
  __syncthreads();
  for (int idx=tid; idx<484; idx+=256){
    int n = idx/22, m = idx - (idx/22)*22;
    float s = 0.f;
    for (int p=0;p<22;p++) s += T1s[n*22+p]*T1s[p*22+m];
    wsT[idx]      = T1s[idx];
    wsT[484+idx]  = 2.f*s - ((n==m)?1.f:0.f);
  }
}

// ---------------- K12: temporal + spatial attention -> S_norm (512 threads) ----
__global__ __launch_bounds__(512) void k_attn(
    const float* __restrict__ x,
    const float* __restrict__ U1, const float* __restrict__ U2, const float* __restrict__ U3,
    const float* __restrict__ be, const float* __restrict__ Ve,
    const float* __restrict__ W1, const float* __restrict__ W2, const float* __restrict__ W3,
    const float* __restrict__ bs, const float* __restrict__ Vs,
    float* __restrict__ snorm){
  int b = blockIdx.x, tid = threadIdx.x;
  const float* xb = x + (size_t)b*22528;
  __shared__ float xu1[1024];
  __shared__ float rhs_t[704];
  __shared__ float lhs_t[704];
  __shared__ float sigp[1024];
  __shared__ float Em[1024];
  __shared__ float sm[1024];
  __shared__ float w1e[32];
  __shared__ float xw3[704];
  __shared__ float lhsS[704];
  __shared__ float lhs2[704];
  __shared__ float rhsS[704];
  __shared__ float sig2[484];
  __shared__ float Sl[484];

  for (int idx=tid; idx<1024; idx+=512){
    float a=0.f;
    for (int n=0;n<22;n++) a = fmaf(xb[n*1024 + idx], U1[n], a);
    xu1[idx]=a;
  }
  for (int idx=tid; idx<704; idx+=512){
    int n = idx>>5, t = idx&31; float a=0.f, c=0.f;
    for (int f=0;f<32;f++){ float xv = xb[n*1024+f*32+t]; a = fmaf(U3[f],xv,a); c = fmaf(W3[f],xv,c); }
    rhs_t[idx]=a; xw3[idx]=c;
  }
  __syncthreads();
  for (int idx=tid; idx<704; idx+=512){
    int t = idx/22, n2 = idx - t*22; float a=0.f;
    for (int f=0;f<32;f++) a = fmaf(xu1[f*32+t], U2[f*22+n2], a);
    lhs_t[idx]=a;
  }
  __syncthreads();
  for (int idx=tid; idx<1024; idx+=512){
    int s = idx>>5, u = idx&31; float p=0.f;
    for (int n=0;n<22;n++) p = fmaf(lhs_t[s*22+n], rhs_t[n*32+u], p);
    sigp[idx] = sigm(p + be[idx]);
  }
  __syncthreads();
  for (int idx=tid; idx<1024; idx+=512){
    int t = idx>>5, u = idx&31; float a=0.f;
    for (int s2=0;s2<32;s2++) a = fmaf(Ve[t*32+s2], sigp[s2*32+u], a);
    Em[idx]=a;
  }
  __syncthreads();
  // ---- temporal softmax over t (axis=1), all 512 threads: u=tid>>4, th=tid&15 ----
  {
    int u = tid>>4, th = tid&15;
    float e0 = Em[(2*th)*32 + u], e1 = Em[(2*th+1)*32 + u];
    float mx = fmaxf(e0, e1);
    #pragma unroll
    for (int mask=1; mask<16; mask<<=1) mx = fmaxf(mx, __shfl_xor(mx, mask));
    float x0 = expf(e0-mx), x1 = expf(e1-mx);
    float s = x0 + x1;
    #pragma unroll
    for (int mask=1; mask<16; mask<<=1) s += __shfl_xor(s, mask);
    float inv = 1.f/s;
    sm[(2*th)*32 + u]   = x0*inv;
    sm[(2*th+1)*32 + u] = x1*inv;
  }
  __syncthreads();
  {
    int u = tid>>4, th = tid&15;
    float pw = fmaf(sm[u*32 + 2*th], W1[2*th], sm[u*32 + 2*th+1]*W1[2*th+1]);
    #pragma unroll
    for (int mask=1; mask<16; mask<<=1) pw += __shfl_xor(pw, mask);
    if (th==0) w1e[u] = pw;
  }
  __syncthreads();
  for (int idx=tid; idx<704; idx+=512){
    int n = idx>>5, f = idx&31; float a=0.f;
    for (int u=0;u<32;u++) a = fmaf(xb[n*1024+f*32+u], w1e[u], a);
    lhsS[idx]=a;
  }
  __syncthreads();
  for (int idx=tid; idx<704; idx+=512){
    int n = idx>>5, t = idx&31; float a=0.f;
    for (int f=0;f<32;f++) a = fmaf(lhsS[n*32+f], W2[f*32+t], a);
    lhs2[idx]=a;
  }
  for (int idx=tid; idx<704; idx+=512){
    int mm = idx>>5, t = idx&31; float a=0.f;
    for (int u=0;u<32;u++) a = fmaf(xw3[mm*32+u], sm[u*32+t], a);
    rhsS[idx]=a;
  }
  __syncthreads();
  for (int idx=tid; idx<484; idx+=512){
    int a_ = idx/22, l = idx - (idx/22)*22; float p=0.f;
    for (int t=0;t<32;t++) p = fmaf(lhs2[a_*32+t], rhsS[l*32+t], p);
    sig2[idx] = sigm(p + bs[idx]);
  }
  __syncthreads();
  for (int idx=tid; idx<484; idx+=512){
    int n = idx/22, l = idx - (idx/22)*22; float s=0.f;
    for (int mm=0;mm<22;mm++) s = fmaf(Vs[n*22+mm], sig2[mm*22+l], s);
    Sl[idx]=s;
  }
  __syncthreads();
  // ---- spatial softmax over n (axis=1), 32-lane groups per l ----
  {
    int grp = tid>>5, nn = tid&31;
    for (int l = grp; l < 22; l += 16){
      float v = (nn<22) ? Sl[nn*22 + l] : -1e30f;
      float mx = v;
      #pragma unroll
      for (int mask=1; mask<32; mask<<=1) mx = fmaxf(mx, __shfl_xor(mx, mask));
      float e = (nn<22) ? expf(v-mx) : 0.f;
      float s = e;
      #pragma unroll
      for (int mask=1; mask<32; mask<<=1) s += __shfl_xor(s, mask);
      if (nn<22) snorm[(size_t)b*484 + nn*22 + l] = e*(1.f/s);
    }
  }
}

// ---------------- Fused m-pair: cheb + Theta MFMA + conv MFMA + LN ----
// LDS tiles GtU/xTU are written transposed; column-BLOCK XOR swizzle kills the
// 8-way write bank conflicts (write banks become an exact 2-way cover).
// Reads apply the same XOR and remain single b128 ops.
__global__ __launch_bounds__(256, 6) void k_fused(
    const float* __restrict__ x,
    const float* __restrict__ wsT, const float* __restrict__ snorm,
    const u16* __restrict__ thA, const u16* __restrict__ wA, const float* __restrict__ wsB,
    const float* __restrict__ lng, const float* __restrict__ lnb,
    float* __restrict__ out){
  __shared__ __align__(16) u16 GtU[2][32*72];   // G^T bf16 [t][64 cols], stride 72, swizzled blocks
  __shared__ __align__(16) u16 sgTU[2][34*72];  // sg^T bf16 [t+1][c], rows 0,33 zero
  __shared__ __align__(16) u16 xTU[2][32*40];   // x[m]^T bf16 [t][f], stride 40, swizzled blocks
  __shared__ __align__(16) float ak4[22*4];     // [n][mi*2+k1]
  __shared__ float smm[2];

  int wg = blockIdx.x;
  int logical = (wg & 7)*1408 + (wg >> 3);      // 11264 = 8*1408 XCD swizzle
  int b = logical/11, mp = logical - b*11;
  int m0 = mp*2;
  int tid = threadIdx.x;
  const float* xb = x + (size_t)b*22528;

  if (tid < 128){                                // zero sg pad rows 0, 33
    int mi = tid>>6, r6 = tid&63;
    int row = (r6>>5) ? 33 : 0, c2 = r6&31;
    *(unsigned*)&sgTU[mi][row*72 + c2*2] = 0u;
  }
  if (tid < 88){
    int n = tid>>2, j = tid&3;                  // j = mi*2 + k1
    int mi = j>>1, k1 = j&1;
    int m = m0 + mi;
    ak4[tid] = wsT[k1*484 + n*22 + m] * snorm[(size_t)b*484 + n*22 + m];
  }
  if (tid < 2) smm[tid] = snorm[(size_t)b*484 + (m0+tid)*23];
  __syncthreads();

  // ---- Phase A: G[k][f][t] = sum_n ak[k][n]*x[n][f][t], k=1,2; + xTU tiles ----
  {
    f32x2 acc[2][2][2];   // [mi][k1][half]
    #pragma unroll
    for (int a=0;a<2;a++)
      #pragma unroll
      for (int k1=0;k1<2;k1++){ acc[a][k1][0]=f32x2{0,0}; acc[a][k1][1]=f32x2{0,0}; }
    const float4* x4 = (const float4*)xb;
    #pragma unroll 2
    for (int n=0;n<22;n++){
      float4 av = *(const float4*)&ak4[n*4];    // single b128 broadcast read
      float4 xv = x4[n*256 + tid];
      f32x2 xlo = {xv.x, xv.y}, xhi = {xv.z, xv.w};
      f32x2 a00 = {av.x, av.x}, a01 = {av.y, av.y};
      f32x2 a10 = {av.z, av.z}, a11 = {av.w, av.w};
      acc[0][0][0] = __builtin_elementwise_fma(a00, xlo, acc[0][0][0]);
      acc[0][0][1] = __builtin_elementwise_fma(a00, xhi, acc[0][0][1]);
      acc[0][1][0] = __builtin_elementwise_fma(a01, xlo, acc[0][1][0]);
      acc[0][1][1] = __builtin_elementwise_fma(a01, xhi, acc[0][1][1]);
      acc[1][0][0] = __builtin_elementwise_fma(a10, xlo, acc[1][0][0]);
      acc[1][0][1] = __builtin_elementwise_fma(a10, xhi, acc[1][0][1]);
      acc[1][1][0] = __builtin_elementwise_fma(a11, xlo, acc[1][1][0]);
      acc[1][1][1] = __builtin_elementwise_fma(a11, xhi, acc[1][1][1]);
    }
    int f = tid>>3, t7 = tid&7, t0 = t7*4;
    int w4 = f>>3, f_low = f&7;                 // w4 == wave id
    // swizzled column starts: GtU block = (k1*4 + w4) ^ t7 ; xTU block = w4 ^ (t7&3)
    int gcol0 = 8*((0*4 + w4) ^ t7) + f_low;
    int gcol1 = 8*((1*4 + w4) ^ t7) + f_low;
    int xcol  = 8*(w4 ^ (t7&3)) + f_low;
    #pragma unroll
    for (int mi=0;mi<2;mi++){
      float4 xm = ((const float4*)xb)[(m0+mi)*256 + tid];
      u16* xd = &xTU[mi][0];
      xd[(t0+0)*40 + xcol] = f2bf(xm.x);
      xd[(t0+1)*40 + xcol] = f2bf(xm.y);
      xd[(t0+2)*40 + xcol] = f2bf(xm.z);
      xd[(t0+3)*40 + xcol] = f2bf(xm.w);
      #pragma unroll
      for (int k1=0;k1<2;k1++){
        int gc = k1 ? gcol1 : gcol0;
        u16* gd = &GtU[mi][gc];
        gd[(t0+0)*72] = f2bf(acc[mi][k1][0][0]);
        gd[(t0+1)*72] = f2bf(acc[mi][k1][0][1]);
        gd[(t0+2)*72] = f2bf(acc[mi][k1][1][0]);
        gd[(t0+3)*72] = f2bf(acc[mi][k1][1][1]);
      }
    }
  }
  __syncthreads();

  int w = tid>>6, l = tid&63, r = l&15, g = l>>4;

  // ---- Phase B: sg[c][t] = relu( sum_{k=1,2} + smm * (Theta0^T x[m]) ), per m ----
  {
    const u16* tA = thA + (size_t)(w*64 + l)*8;
    short8 a0 = *(const short8*)(tA);
    short8 a1 = *(const short8*)(tA + 2048);
    short8 a2 = *(const short8*)(tA + 4096);
    #pragma unroll
    for (int mi=0;mi<2;mi++){
      float sm_ = smm[mi];
      #pragma unroll
      for (int ti=0; ti<2; ++ti){
        int row = ti*16 + r;
        int h  = (row>>2)&7;                    // GtU swizzle key
        int h2 = (row>>2)&3;                    // xTU swizzle key
        f32x4 a12 = {0.f,0.f,0.f,0.f}, ax = {0.f,0.f,0.f,0.f};
        const u16* gp0 = &GtU[mi][row*72 + 8*((0*4+g)^h)];
        const u16* gp1 = &GtU[mi][row*72 + 8*((1*4+g)^h)];
        a12 = __builtin_amdgcn_mfma_f32_16x16x32_bf16(a1, *(const short8*)(gp0), a12, 0,0,0);
        a12 = __builtin_amdgcn_mfma_f32_16x16x32_bf16(a2, *(const short8*)(gp1), a12, 0,0,0);
        const u16* xp = &xTU[mi][row*40 + 8*(g^h2)];
        ax  = __builtin_amdgcn_mfma_f32_16x16x32_bf16(a0, *(const short8*)(xp),  ax,  0,0,0);
        int orow = 1 + row, c0 = w*16 + g*4;
        float v0 = fmaxf(fmaf(sm_, ax[0], a12[0]), 0.f);
        float v1 = fmaxf(fmaf(sm_, ax[1], a12[1]), 0.f);
        float v2 = fmaxf(fmaf(sm_, ax[2], a12[2]), 0.f);
        float v3 = fmaxf(fmaf(sm_, ax[3], a12[3]), 0.f);
        *(unsigned*)&sgTU[mi][orow*72 + c0]     = f2bf2(v0, v1);
        *(unsigned*)&sgTU[mi][orow*72 + c0 + 2] = f2bf2(v2, v3);
      }
    }
  }
  __syncthreads();

  // ---- Phase C: y[o][t] = sum_k W[k][o]*B[k][t], K=224, per m ----
  f32x4 acc[2][2];
  acc[0][0]=f32x4{0,0,0,0}; acc[0][1]=f32x4{0,0,0,0};
  acc[1][0]=f32x4{0,0,0,0}; acc[1][1]=f32x4{0,0,0,0};
  {
    const u16* pA = wA + (size_t)(w*64 + l)*8;
    #pragma unroll
    for (int ks=0; ks<6; ++ks){
      short8 wk = *(const short8*)(pA + ks*2048);
      int seg = ks>>1, colb = (ks&1)*32 + 8*g;
      #pragma unroll
      for (int mi=0;mi<2;mi++){
        const u16* q0 = &sgTU[mi][(r + seg)*72 + colb];
        acc[mi][0] = __builtin_amdgcn_mfma_f32_16x16x32_bf16(wk, *(const short8*)(q0),         acc[mi][0], 0,0,0);
        acc[mi][1] = __builtin_amdgcn_mfma_f32_16x16x32_bf16(wk, *(const short8*)(q0 + 16*72), acc[mi][1], 0,0,0);
      }
    }
    short8 wk = *(const short8*)(pA + 6*2048);
    int h2 = (r>>2)&3;                          // same key for rows r and 16+r
    #pragma unroll
    for (int mi=0;mi<2;mi++){
      const u16* q = &xTU[mi][r*40 + 8*(g^h2)];
      acc[mi][0] = __builtin_amdgcn_mfma_f32_16x16x32_bf16(wk, *(const short8*)(q),         acc[mi][0], 0,0,0);
      acc[mi][1] = __builtin_amdgcn_mfma_f32_16x16x32_bf16(wk, *(const short8*)(q + 16*40), acc[mi][1], 0,0,0);
    }
  }

  // ---- Epilogue: bias + relu + LN over o per t, both m ----
  float4 bias4 = ((const float4*)wsB)[w*4 + g];
  float bb[4] = {bias4.x, bias4.y, bias4.z, bias4.w};
  float y[2][2][4];
  float s1[2][2] = {{0.f,0.f},{0.f,0.f}}, s2[2][2] = {{0.f,0.f},{0.f,0.f}};
  #pragma unroll
  for (int mi=0;mi<2;mi++){
    #pragma unroll
    for (int h=0;h<2;h++){
      #pragma unroll
      for (int i=0;i<4;i++){
        float v = fmaxf(acc[mi][h][i] + bb[i], 0.f);
        y[mi][h][i] = v;
        s1[mi][h] += v;
        s2[mi][h] = fmaf(v, v, s2[mi][h]);
      }
      s1[mi][h] += __shfl_xor(s1[mi][h],16); s1[mi][h] += __shfl_xor(s1[mi][h],32);
      s2[mi][h] += __shfl_xor(s2[mi][h],16); s2[mi][h] += __shfl_xor(s2[mi][h],32);
    }
  }
  float* p1 = (float*)&GtU[0][0];     // overlay: [mi*32+t][4w] sums, then sumsq at +256
  float* p2 = p1 + 256;
  if (l < 16){
    #pragma unroll
    for (int mi=0;mi<2;mi++){
      p1[(mi*32 + l)*4 + w]      = s1[mi][0];
      p1[(mi*32 + 16 + l)*4 + w] = s1[mi][1];
      p2[(mi*32 + l)*4 + w]      = s2[mi][0];
      p2[(mi*32 + 16 + l)*4 + w] = s2[mi][1];
    }
  }
  __syncthreads();
  float4 g4 = ((const float4*)lng)[w*4 + g];
  float4 b4 = ((const float4*)lnb)[w*4 + g];
  float gg[4]={g4.x,g4.y,g4.z,g4.w}, bgg[4]={b4.x,b4.y,b4.z,b4.w};
  #pragma unroll
  for (int mi=0;mi<2;mi++){
    float4 q1a = ((const float4*)p1)[mi*32 + r],      q2a = ((const float4*)p2)[mi*32 + r];
    float4 q1b = ((const float4*)p1)[mi*32 + 16 + r], q2b = ((const float4*)p2)[mi*32 + 16 + r];
    float S1a = q1a.x+q1a.y+q1a.z+q1a.w, S2a = q2a.x+q2a.y+q2a.z+q2a.w;
    float S1b = q1b.x+q1b.y+q1b.z+q1b.w, S2b = q2b.x+q2b.y+q2b.z+q2b.w;
    float mu0 = S1a*(1.f/64.f), var0 = S2a*(1.f/64.f) - mu0*mu0, rs0 = rsqrtf(var0 + 1e-5f);
    float mu1 = S1b*(1.f/64.f), var1 = S2b*(1.f/64.f) - mu1*mu1, rs1 = rsqrtf(var1 + 1e-5f);
    float* ob = out + ((size_t)(b*22 + m0 + mi)*64 + (w*16 + g*4))*32;
    #pragma unroll
    for (int i=0;i<4;i++){
      ob[i*32 + r]      = (y[mi][0][i]-mu0)*rs0*gg[i] + bgg[i];
      ob[i*32 + 16 + r] = (y[mi][1][i]-mu1)*rs1*gg[i] + bgg[i];
    }
  }
}

extern "C" void kernel_launch(void* const* d_in, const int* in_sizes, int n_in,
                              void* d_out, int out_size, void* d_ws, size_t ws_size,
                              hipStream_t stream){
  const float* x     = (const float*)d_in[0];
  const float* U1    = (const float*)d_in[1];
  const float* U2    = (const float*)d_in[2];
  const float* U3    = (const float*)d_in[3];
  const float* be    = (const float*)d_in[4];
  const float* Ve    = (const float*)d_in[5];
  const float* W1    = (const float*)d_in[6];
  const float* W2    = (const float*)d_in[7];
  const float* W3    = (const float*)d_in[8];
  const float* bs    = (const float*)d_in[9];
  const float* Vs    = (const float*)d_in[10];
  const float* Theta = (const float*)d_in[11];
  const float* emb   = (const float*)d_in[12];
  const float* tw    = (const float*)d_in[13];
  const float* tb    = (const float*)d_in[14];
  const float* rw    = (const float*)d_in[15];
  const float* rb    = (const float*)d_in[16];
  const float* lng   = (const float*)d_in[17];
  const float* lnb   = (const float*)d_in[18];
  float* out = (float*)d_out;
  float* wsf = (float*)d_ws;
  float* wsT   = wsf;                        // 968 floats (pad to 1024)
  float* snorm = wsf + 1024;                 // 1024*484 floats
  u16*   thA   = (u16*)(wsf + 496640);       // 6144 u16
  u16*   wA    = (u16*)(wsf + 499712);       // 14336 u16
  float* wsB   = wsf + 506880;               // 64 floats

  k_sup_prep<<<82, 256, 0, stream>>>(emb, wsT, Theta, tw, tb, rw, rb, thA, wA, wsB);
  k_attn<<<1024, 512, 0, stream>>>(x, U1,U2,U3, be,Ve, W1,W2,W3, bs,Vs, snorm);
  k_fused<<<1024*11, 256, 0, stream>>>(x, wsT, snorm, thA, wA, wsB, lng, lnb, out);
}